// Round 1
// 1220.587 us; speedup vs baseline: 1.0522x; 1.0522x over previous
//
#include <hip/hip_runtime.h>
#include <math.h>

#define LSEQ 384
#define HD 256
#define PDIM 64
#define NHEAD 4
#define NBINS 65
#define BATCH 2
#define NTT (LSEQ / 16)
#define NTRI (NTT * (NTT + 1) / 2)

typedef __attribute__((ext_vector_type(8))) short bf16x8;
typedef __attribute__((ext_vector_type(16))) float f32x16;
#define MFMA32(a, b, c) __builtin_amdgcn_mfma_f32_32x32x16_bf16(a, b, c, 0, 0, 0)

// ---- DPP-based wave64 reductions (VALU pipe, not LDS) ----
template<int CTRL, int RMASK>
__device__ __forceinline__ float dpp_sum_step(float v) {
    int x = __builtin_amdgcn_update_dpp(0, __float_as_int(v), CTRL, RMASK, 0xf, true);
    return v + __int_as_float(x);
}
template<int CTRL, int RMASK>
__device__ __forceinline__ float dpp_max_step(float v) {
    int x = __builtin_amdgcn_update_dpp(__float_as_int(v), __float_as_int(v), CTRL, RMASK, 0xf, false);
    return fmaxf(v, __int_as_float(x));
}
__device__ __forceinline__ float wsum(float v) {
    v = dpp_sum_step<0x111, 0xf>(v);
    v = dpp_sum_step<0x112, 0xf>(v);
    v = dpp_sum_step<0x114, 0xf>(v);
    v = dpp_sum_step<0x118, 0xf>(v);
    v = dpp_sum_step<0x142, 0xa>(v);
    v = dpp_sum_step<0x143, 0xc>(v);
    return __int_as_float(__builtin_amdgcn_readlane(__float_as_int(v), 63));
}
__device__ __forceinline__ float wmax(float v) {
    v = dpp_max_step<0x111, 0xf>(v);
    v = dpp_max_step<0x112, 0xf>(v);
    v = dpp_max_step<0x114, 0xf>(v);
    v = dpp_max_step<0x118, 0xf>(v);
    v = dpp_max_step<0x142, 0xa>(v);
    v = dpp_max_step<0x143, 0xc>(v);
    return __int_as_float(__builtin_amdgcn_readlane(__float_as_int(v), 63));
}
__device__ __forceinline__ float gelu_erf(float x) {
    return 0.5f * x * (1.0f + erff(x * 0.70710678f));
}

// bf16 RNE conversion + error-compensated split: x ~= hi + lo
__device__ __forceinline__ unsigned short f2bf(float x) {
    unsigned u = __float_as_uint(x);
    unsigned r = (u + 0x7fff + ((u >> 16) & 1)) >> 16;
    return (unsigned short)r;
}
__device__ __forceinline__ float bf2f(unsigned short h) {
    return __uint_as_float(((unsigned)h) << 16);
}
__device__ __forceinline__ void split_bf(float x, unsigned short& h, unsigned short& l) {
    h = f2bf(x);
    l = f2bf(x - bf2f(h));
}

// h[b,l,:] = x[b,l,:] @ rp_w + rp_b + pos[l,:]
__global__ void k_h_init(const float* __restrict__ x, const float* __restrict__ rp_w,
                         const float* __restrict__ rp_b, const float* __restrict__ pos,
                         float* __restrict__ h) {
    __shared__ float xs[48];
    int row = blockIdx.x;            // b*L + l
    int l = row % LSEQ;
    int t = threadIdx.x;
    if (t < 48) xs[t] = x[row * 48 + t];
    __syncthreads();
    float acc = rp_b[t] + pos[l * HD + t];
#pragma unroll 8
    for (int a = 0; a < 48; ++a) acc += xs[a] * rp_w[a * HD + t];
    h[row * HD + t] = acc;
}

// pA[row,:] = h[row,:] @ wA (+ bA);  pB[row,:] = h[row,:] @ wB (+ bB)
// center!=0: subtract per-row mean (LN-mean elimination downstream)
__global__ void k_proj2(const float* __restrict__ h, const float* __restrict__ wA,
                        const float* __restrict__ wB, const float* __restrict__ bA,
                        const float* __restrict__ bB, int center,
                        float* __restrict__ pA, float* __restrict__ pB) {
    __shared__ float hs[HD];
    int row = blockIdx.x;
    int t = threadIdx.x;
    hs[t] = h[row * HD + t];
    hs[t + 128] = h[row * HD + t + 128];
    __syncthreads();
    int col = t & 63;
    const float* w = (t < 64) ? wA : wB;
    const float* bias = (t < 64) ? bA : bB;
    float acc = bias ? bias[col] : 0.0f;
#pragma unroll 8
    for (int a = 0; a < HD; ++a) acc += hs[a] * w[a * PDIM + col];
    if (center) {
        float mean = wsum(acc) * (1.0f / PDIM);
        acc -= mean;
    }
    float* p = (t < 64) ? pA : pB;
    p[row * PDIM + col] = acc;
}

// pair[b,i,j,:] = pi[b,i,:] + pj[b,j,:] + rel_emb[clip(j-i)+32,:]
__global__ void k_pair_init(const float* __restrict__ pi, const float* __restrict__ pj,
                            const float* __restrict__ rel_emb, float* __restrict__ pair) {
    __shared__ float pis[PDIM];
    int row = blockIdx.x;            // b*L + i
    int b = row / LSEQ, i = row % LSEQ;
    int t = threadIdx.x;
    if (t < PDIM) pis[t] = pi[row * PDIM + t];
    __syncthreads();
    const float* pjb = pj + (size_t)b * LSEQ * PDIM;
    float* pr = pair + (size_t)row * LSEQ * PDIM;
    for (int n = t; n < LSEQ * PDIM; n += 256) {
        int j = n >> 6, d = n & 63;
        int r = j - i; r = r < -32 ? -32 : (r > 32 ? 32 : r); r += 32;
        pr[n] = pis[d] + pjb[j * PDIM + d] + rel_emb[r * PDIM + d];
    }
}

// prep: fold LN g/b into W1 (b1p = b1 + bb@W1), split all pair-MLP weights into
// bf16 hi/lo, stored TRANSPOSED [out][k] for direct 16B MFMA A-frag loads.
__global__ void k_prep(const float* __restrict__ pu_ln_g, const float* __restrict__ pu_ln_b,
                       const float* __restrict__ pu_w1, const float* __restrict__ pu_b1,
                       const float* __restrict__ pu_w2,
                       const float* __restrict__ dh_ln_g, const float* __restrict__ dh_ln_b,
                       const float* __restrict__ dh_w1, const float* __restrict__ dh_b1,
                       const float* __restrict__ dh_w2,
                       unsigned short* __restrict__ w1hT, unsigned short* __restrict__ w1lT,
                       unsigned short* __restrict__ w2hT, unsigned short* __restrict__ w2lT,
                       float* __restrict__ b1p, float* __restrict__ w2c) {
    int i = blockIdx.x;              // 0..4
    int c = threadIdx.x;             // 0..63 = output row of transposed arrays
    const float *g, *bb, *w1, *b1, *w2;
    int w2s;
    if (i < 4) { g = pu_ln_g + i * 64; bb = pu_ln_b + i * 64; w1 = pu_w1 + i * 4096;
                 b1 = pu_b1 + i * 64; w2 = pu_w2 + i * 4096; w2s = 64; }
    else       { g = dh_ln_g; bb = dh_ln_b; w1 = dh_w1; b1 = dh_b1; w2 = dh_w2; w2s = 65; }
    float accb = b1[c];
    for (int k = 0; k < 64; ++k) {
        float wv = w1[k * 64 + c];
        accb += bb[k] * wv;
        unsigned short h, l;
        split_bf(g[k] * wv, h, l);                 // W1'[k][c] stored at [c][k]
        w1hT[i * 4096 + c * 64 + k] = h;
        w1lT[i * 4096 + c * 64 + k] = l;
        split_bf(w2[k * w2s + c], h, l);           // W2[k][c] stored at [c][k]
        w2hT[i * 4096 + c * 64 + k] = h;
        w2lT[i * 4096 + c * 64 + k] = l;
    }
    b1p[i * 64 + c] = accb;
    if (i == 4) w2c[c] = dh_w2[c * 65 + 64];
}

// prep for fused mask: gp[li][c] = ln_pair_g[li+1][c] * pbs[c], cb[li] = sum_c ln_pair_b[li+1][c]*pbs[c]
// where pbs[c] = sum_h pb_w[li+1][c][h].  li = 0..2 covers layers 1..3.
__global__ void k_maskprep(const float* __restrict__ g, const float* __restrict__ bb,
                           const float* __restrict__ pbw, float* __restrict__ gp,
                           float* __restrict__ cb) {
    int li = blockIdx.x + 1;         // layer 1..3
    int c = threadIdx.x;             // 0..63 (one wave)
    const float* pw = pbw + li * PDIM * NHEAD;
    float pbs = pw[c * 4] + pw[c * 4 + 1] + pw[c * 4 + 2] + pw[c * 4 + 3];
    gp[blockIdx.x * 64 + c] = g[li * 64 + c] * pbs;
    float s = wsum(bb[li * 64 + c] * pbs);
    if (c == 0) cb[blockIdx.x] = s;
}

// prep: split+transpose seq weights to bf16 hi/lo [n][k] via 64x64 LDS tiles.
// src: [K][N] row-major, per-layer stride sstride; dst: [N][K], stride dstride.
__global__ void k_split_T(const float* __restrict__ src, unsigned short* __restrict__ dh,
                          unsigned short* __restrict__ dl, int K, int N,
                          int tiles_k, int tiles_n, size_t sstride, size_t dstride) {
    __shared__ float lds[64][65];
    int bid = blockIdx.x;
    int tpl = tiles_k * tiles_n;
    int layer = bid / tpl;
    int rest = bid % tpl;
    int kt = rest / tiles_n, nt = rest % tiles_n;
    const float* s = src + layer * sstride;
    int t = threadIdx.x, c = t & 63, r0 = t >> 6;
    for (int r = r0; r < 64; r += 4)
        lds[r][c] = s[(size_t)(kt * 64 + r) * N + nt * 64 + c];
    __syncthreads();
    unsigned short* oh = dh + layer * dstride;
    unsigned short* ol = dl + layer * dstride;
    for (int r = r0; r < 64; r += 4) {
        float v = lds[c][r];                       // src[kt*64+c][nt*64+r]
        unsigned short h, l;
        split_bf(v, h, l);
        size_t o = (size_t)(nt * 64 + r) * K + kt * 64 + c;
        oh[o] = h;
        ol[o] = l;
    }
}

// ============ generic MFMA seq GEMM ============
// OUT[m][n] = epi( X[m][:]@W + bias[n] + (R?R[m][n]:0) ), M=768 rows.
// W pre-split bf16 hi/lo transposed [n][k]. Wave = 32x32 tile, block = 4 waves.
template<bool GELU>
__global__ void __launch_bounds__(256) k_gemm(
    const float* __restrict__ X, const unsigned short* __restrict__ wTh,
    const unsigned short* __restrict__ wTl, const float* __restrict__ bias,
    const float* __restrict__ R, float* __restrict__ OUT, int K, int N) {
    int idx = blockIdx.x * 4 + (threadIdx.x >> 6);
    int lane = threadIdx.x & 63;
    int pl = lane & 31, hq = lane >> 5;
    int ntiles = N >> 5;
    int mt = idx / ntiles, nt = idx % ntiles;
    const float* xr = X + (size_t)(mt * 32 + pl) * K + 8 * hq;
    const unsigned short* bh = wTh + (size_t)(nt * 32 + pl) * K + 8 * hq;
    const unsigned short* bl = wTl + (size_t)(nt * 32 + pl) * K + 8 * hq;
    int n = nt * 32 + pl;
    float bv = bias[n];
    f32x16 acc;
#pragma unroll
    for (int r = 0; r < 16; ++r) {
        int mr = mt * 32 + (r & 3) + 8 * (r >> 2) + 4 * hq;
        acc[r] = bv + (R ? R[(size_t)mr * N + n] : 0.0f);
    }
#pragma unroll 4
    for (int s = 0; s < K; s += 16) {
        bf16x8 ah, al;
#pragma unroll
        for (int j = 0; j < 8; ++j) {
            unsigned short h, l;
            split_bf(xr[s + j], h, l);
            ah[j] = (short)h; al[j] = (short)l;
        }
        bf16x8 bhv = *(const bf16x8*)(bh + s);
        bf16x8 blv = *(const bf16x8*)(bl + s);
        acc = MFMA32(ah, bhv, acc);
        acc = MFMA32(al, bhv, acc);
        acc = MFMA32(ah, blv, acc);
    }
#pragma unroll
    for (int r = 0; r < 16; ++r) {
        int mr = mt * 32 + (r & 3) + 8 * (r >> 2) + 4 * hq;
        float v = acc[r];
        OUT[(size_t)mr * N + n] = GELU ? gelu_erf(v) : v;
    }
}

// mask[l,m] = (1/(B*NH)) * sum_b LN(pair[b,l,m,:]) . pbsum   (used for layer 0 only)
__global__ void k_mask(const float* __restrict__ pair, const float* __restrict__ g,
                       const float* __restrict__ bb, const float* __restrict__ pbw,
                       float* __restrict__ mask) {
    int wid = (blockIdx.x * 4 + (threadIdx.x >> 6)) * 2;
    int lane = threadIdx.x & 63;
    int l = wid / LSEQ, m0 = wid % LSEQ;
    float gd = g[lane], bd = bb[lane];
    float pbs = pbw[lane * 4] + pbw[lane * 4 + 1] + pbw[lane * 4 + 2] + pbw[lane * 4 + 3];
    float v[4];
#pragma unroll
    for (int s = 0; s < 4; ++s) {
        int b = s >> 1, m = m0 + (s & 1);
        v[s] = pair[(((size_t)(b * LSEQ + l)) * LSEQ + m) * PDIM + lane];
    }
    float mean[4], d[4], var[4], dot[4];
#pragma unroll
    for (int s = 0; s < 4; ++s) mean[s] = wsum(v[s]) * (1.0f / PDIM);
#pragma unroll
    for (int s = 0; s < 4; ++s) d[s] = v[s] - mean[s];
#pragma unroll
    for (int s = 0; s < 4; ++s) var[s] = wsum(d[s] * d[s]) * (1.0f / PDIM);
#pragma unroll
    for (int s = 0; s < 4; ++s) {
        float ln = d[s] * rsqrtf(var[s] + 1e-5f) * gd + bd;
        dot[s] = wsum(ln * pbs);
    }
    if (lane == 0) {
        mask[l * LSEQ + m0]     = (dot[0] + dot[2]) * (1.0f / (BATCH * NHEAD));
        mask[l * LSEQ + m0 + 1] = (dot[1] + dot[3]) * (1.0f / (BATCH * NHEAD));
    }
}

// seq layernorm: one row per block
__global__ void k_ln_seq(const float* __restrict__ h, const float* __restrict__ g,
                         const float* __restrict__ b, float* __restrict__ out) {
    __shared__ float red[8];
    int row = blockIdx.x;
    int t = threadIdx.x;
    int w = t >> 6, lane = t & 63;
    float v = h[row * HD + t];
    float s = wsum(v);
    if (lane == 0) red[w] = s;
    __syncthreads();
    float mean = (red[0] + red[1] + red[2] + red[3]) * (1.0f / HD);
    float d = v - mean;
    float q = wsum(d * d);
    if (lane == 0) red[4 + w] = q;
    __syncthreads();
    float var = (red[4] + red[5] + red[6] + red[7]) * (1.0f / HD);
    out[row * HD + t] = d * rsqrtf(var + 1e-5f) * g[t] + b[t];
}

// attention for one (b, nh, l) per block
__global__ void k_attn(const float* __restrict__ qkv, const float* __restrict__ mask,
                       float* __restrict__ o) {
    __shared__ __align__(16) float qs[64];
    __shared__ float sc[LSEQ];
    __shared__ float red[8];
    __shared__ float op[4][64];
    int bid = blockIdx.x;
    int l = bid % LSEQ;
    int nh = (bid / LSEQ) & 3;
    int b = bid / (LSEQ * NHEAD);
    int t = threadIdx.x;
    int w = t >> 6, lane = t & 63;
    const float* qbase = qkv + ((size_t)(b * LSEQ + l)) * 768 + nh * 64;
    if (t < 64) qs[t] = qbase[t];
    __syncthreads();
    float lmax = -1e30f;
    float myv[2];
#pragma unroll
    for (int it = 0; it < 2; ++it) {
        int m = t + it * 256;
        if (m < LSEQ) {
            const float* kb = qkv + ((size_t)(b * LSEQ + m)) * 768 + 256 + nh * 64;
            const float4* k4 = (const float4*)kb;
            const float4* q4 = (const float4*)qs;
            float acc = 0.0f;
#pragma unroll
            for (int a = 0; a < 16; ++a) {
                float4 kv = k4[a], qv = q4[a];
                acc += qv.x * kv.x + qv.y * kv.y + qv.z * kv.z + qv.w * kv.w;
            }
            float s = acc * 0.125f + mask[l * LSEQ + m];
            myv[it] = s;
            lmax = fmaxf(lmax, s);
        } else myv[it] = -1e30f;
    }
    float wm = wmax(lmax);
    if (lane == 0) red[w] = wm;
    __syncthreads();
    float gmax = fmaxf(fmaxf(red[0], red[1]), fmaxf(red[2], red[3]));
    float lsum = 0.0f;
#pragma unroll
    for (int it = 0; it < 2; ++it) {
        int m = t + it * 256;
        if (m < LSEQ) {
            float e = expf(myv[it] - gmax);
            sc[m] = e;
            lsum += e;
        }
    }
    float ws = wsum(lsum);
    if (lane == 0) red[4 + w] = ws;
    __syncthreads();
    float inv = 1.0f / (red[4] + red[5] + red[6] + red[7]);
    int d = t & 63, gq = t >> 6;
    float part = 0.0f;
    for (int m = gq * 96; m < (gq + 1) * 96; ++m)
        part += sc[m] * qkv[((size_t)(b * LSEQ + m)) * 768 + 512 + nh * 64 + d];
    op[gq][d] = part;
    __syncthreads();
    if (t < 64) {
        float ov = (op[0][t] + op[1][t] + op[2][t] + op[3][t]) * inv;
        o[((size_t)(b * LSEQ + l)) * HD + nh * 64 + t] = ov;
    }
}

// ============ MFMA pair-update (+ fused next-layer mask) ============
// LDS-staged: block's 128x64 pair region is read AND written as contiguous
// coalesced float4; per-lane channel access goes through [128][65] LDS
// (stride 65 -> 2-way bank aliasing, free). If mask_out != null, the final
// pair vector (already in regs) also produces the NEXT layer's attention
// mask contribution: dot = rs * sum(d * g*pbs) + sum(b*pbs), atomically
// accumulated over b into a pre-zeroed buffer.
__global__ void __launch_bounds__(256) k_pair_upd(
    const float* __restrict__ ojc,   // centered oj         (B,L,64)
    const float* __restrict__ oic,   // centered oi+outer_b (B,L,64)
    const unsigned short* __restrict__ w1hT, const unsigned short* __restrict__ w1lT,
    const float* __restrict__ b1p,
    const unsigned short* __restrict__ w2hT, const unsigned short* __restrict__ w2lT,
    const float* __restrict__ b2, float* __restrict__ pair,
    const float* __restrict__ gpb, const float* __restrict__ cbv,
    float* __restrict__ mask_out) {
    __shared__ float pt[128][65];
    __shared__ float gpl[64];
    int blk = blockIdx.x;            // row*3 + seg
    int row = blk / 3, seg = blk % 3;
    int b = row / LSEQ;
    int t = threadIdx.x;
    int wave = t >> 6, lane = t & 63;
    int pl = lane & 31, hq = lane >> 5;
    int pv = wave * 32 + pl;
    int p = seg * 128 + pv;                      // j index within pair row
    const float* ojr = ojc + ((size_t)b * LSEQ + p) * 64;
    const float* oir = oic + (size_t)row * 64;
    float* prblk = pair + ((size_t)row * LSEQ + seg * 128) * 64;

    // stage-in: contiguous 32KB pair region -> LDS (residual read)
    const float4* src4 = (const float4*)prblk;
    for (int n = t; n < 2048; n += 256) {
        float4 g4 = src4[n];
        int pv2 = n >> 4, ch = (n & 15) << 2;
        pt[pv2][ch] = g4.x; pt[pv2][ch + 1] = g4.y;
        pt[pv2][ch + 2] = g4.z; pt[pv2][ch + 3] = g4.w;
    }
    if (mask_out && t < 64) gpl[t] = gpb[t];

    float v[32];
#pragma unroll
    for (int s = 0; s < 4; ++s) {
        int k0 = 16 * s + 8 * hq;
#pragma unroll
        for (int j = 0; j < 8; ++j) v[8 * s + j] = ojr[k0 + j] + oir[k0 + j];
    }
    float ss = 0.0f;
#pragma unroll
    for (int i = 0; i < 32; ++i) ss = fmaf(v[i], v[i], ss);
    ss += __shfl_xor(ss, 32);
    float rs = rsqrtf(ss * (1.0f / PDIM) + 1e-5f);
    bf16x8 zh[4], zl[4];
#pragma unroll
    for (int s = 0; s < 4; ++s)
#pragma unroll
        for (int j = 0; j < 8; ++j) {
            unsigned short h, l;
            split_bf(v[8 * s + j] * rs, h, l);
            zh[s][j] = (short)h; zl[s][j] = (short)l;
        }

    f32x16 acc0, acc1;
#pragma unroll
    for (int r = 0; r < 16; ++r) {
        int rr = (r & 3) + 8 * (r >> 2) + 4 * hq;
        acc0[r] = b1p[rr];
        acc1[r] = b1p[32 + rr];
    }
#pragma unroll
    for (int s = 0; s < 4; ++s) {
        int ko = 16 * s + 8 * hq;
        bf16x8 a0h = *(const bf16x8*)(w1hT + (pl << 6) + ko);
        bf16x8 a0l = *(const bf16x8*)(w1lT + (pl << 6) + ko);
        bf16x8 a1h = *(const bf16x8*)(w1hT + ((32 + pl) << 6) + ko);
        bf16x8 a1l = *(const bf16x8*)(w1lT + ((32 + pl) << 6) + ko);
        acc0 = MFMA32(a0h, zh[s], acc0);
        acc0 = MFMA32(a0h, zl[s], acc0);
        acc0 = MFMA32(a0l, zh[s], acc0);
        acc1 = MFMA32(a1h, zh[s], acc1);
        acc1 = MFMA32(a1h, zl[s], acc1);
        acc1 = MFMA32(a1l, zh[s], acc1);
    }
    float u0[16], u1[16];
#pragma unroll
    for (int r = 0; r < 16; ++r) { u0[r] = gelu_erf(acc0[r]); u1[r] = gelu_erf(acc1[r]); }

    float rA0[4], rB0[4], rA1[4], rB1[4];
#pragma unroll
    for (int i = 0; i < 4; ++i) {
        rA0[i] = __shfl_xor(hq ? u0[i] : u0[4 + i], 32);
        rB0[i] = __shfl_xor(hq ? u0[8 + i] : u0[12 + i], 32);
        rA1[i] = __shfl_xor(hq ? u1[i] : u1[4 + i], 32);
        rB1[i] = __shfl_xor(hq ? u1[8 + i] : u1[12 + i], 32);
    }
    bf16x8 uh[4], ul[4];
#pragma unroll
    for (int s = 0; s < 4; ++s) {
        int tt = s >> 1, q = s & 1;
#pragma unroll
        for (int i = 0; i < 4; ++i) {
            float own_f = q ? (tt ? u1[8 + i] : u0[8 + i]) : (tt ? u1[i] : u0[i]);
            float own_s = q ? (tt ? u1[12 + i] : u0[12 + i]) : (tt ? u1[4 + i] : u0[4 + i]);
            float rcv   = q ? (tt ? rB1[i] : rB0[i]) : (tt ? rA1[i] : rA0[i]);
            float f  = hq ? rcv : own_f;
            float g2 = hq ? own_s : rcv;
            unsigned short h, l;
            split_bf(f, h, l);  uh[s][i] = (short)h;     ul[s][i] = (short)l;
            split_bf(g2, h, l); uh[s][4 + i] = (short)h; ul[s][4 + i] = (short)l;
        }
    }

    __syncthreads();  // stage-in complete before residual reads
    f32x16 c0, c1;
#pragma unroll
    for (int r = 0; r < 16; ++r) {
        int rr = (r & 3) + 8 * (r >> 2) + 4 * hq;
        c0[r] = b2[rr] + pt[pv][rr];
        c1[r] = b2[32 + rr] + pt[pv][32 + rr];
    }
#pragma unroll
    for (int s = 0; s < 4; ++s) {
        int ko = 16 * s + 8 * hq;
        bf16x8 a0h = *(const bf16x8*)(w2hT + (pl << 6) + ko);
        bf16x8 a0l = *(const bf16x8*)(w2lT + (pl << 6) + ko);
        bf16x8 a1h = *(const bf16x8*)(w2hT + ((32 + pl) << 6) + ko);
        bf16x8 a1l = *(const bf16x8*)(w2lT + ((32 + pl) << 6) + ko);
        c0 = MFMA32(a0h, uh[s], c0);
        c0 = MFMA32(a0h, ul[s], c0);
        c0 = MFMA32(a0l, uh[s], c0);
        c1 = MFMA32(a1h, uh[s], c1);
        c1 = MFMA32(a1h, ul[s], c1);
        c1 = MFMA32(a1l, uh[s], c1);
    }
    // write final pair values back to LDS (same slots this lane read; no race)
#pragma unroll
    for (int r = 0; r < 16; ++r) {
        int rr = (r & 3) + 8 * (r >> 2) + 4 * hq;
        pt[pv][rr] = c0[r];
        pt[pv][32 + rr] = c1[r];
    }
    // fused mask for next layer: LN(final pair) . pbsum, mean over b via atomics
    if (mask_out) {
        float sv = 0.0f;
#pragma unroll
        for (int r = 0; r < 16; ++r) sv += c0[r] + c1[r];
        sv += __shfl_xor(sv, 32);
        float mean = sv * (1.0f / PDIM);
        float sd2 = 0.0f, sdg = 0.0f;
#pragma unroll 4
        for (int r = 0; r < 16; ++r) {
            int rr = (r & 3) + 8 * (r >> 2) + 4 * hq;
            float d0 = c0[r] - mean, d1 = c1[r] - mean;
            sd2 = fmaf(d0, d0, sd2);
            sd2 = fmaf(d1, d1, sd2);
            sdg = fmaf(d0, gpl[rr], sdg);
            sdg = fmaf(d1, gpl[32 + rr], sdg);
        }
        sd2 += __shfl_xor(sd2, 32);
        sdg += __shfl_xor(sdg, 32);
        float rsv = rsqrtf(sd2 * (1.0f / PDIM) + 1e-5f);
        float dot = rsv * sdg + cbv[0];
        if (hq == 0)
            atomicAdd(mask_out + (row % LSEQ) * LSEQ + p, dot * (1.0f / (BATCH * NHEAD)));
    }
    __syncthreads();
    // stage-out: LDS -> contiguous coalesced float4 stores
    float4* dst4 = (float4*)prblk;
    for (int n = t; n < 2048; n += 256) {
        int pv2 = n >> 4, ch = (n & 15) << 2;
        float4 g4 = { pt[pv2][ch], pt[pv2][ch + 1], pt[pv2][ch + 2], pt[pv2][ch + 3] };
        dst4[n] = g4;
    }
}

// ============ MFMA distogram head ============
// Epilogue stages the 128x65 output tile in LDS, then writes one contiguous
// 33KB region as coalesced float4 (was: 33 scattered 4B stores per lane).
__global__ void __launch_bounds__(256) k_dist(
    const float* __restrict__ pair,
    const unsigned short* __restrict__ w1hT, const unsigned short* __restrict__ w1lT,
    const float* __restrict__ b1p,
    const unsigned short* __restrict__ w2hT, const unsigned short* __restrict__ w2lT,
    const float* __restrict__ w2c, const float* __restrict__ b2,
    float* __restrict__ out) {
    __shared__ __align__(16) float ot[128][NBINS];
    int blk = blockIdx.x;
    int row = blk / 3, seg = blk % 3;
    int t = threadIdx.x;
    int wave = t >> 6, lane = t & 63;
    int pl = lane & 31, hq = lane >> 5;
    int pv = wave * 32 + pl;
    int p = seg * 128 + pv;
    const float* prp = pair + ((size_t)row * LSEQ + p) * 64;
    float v[32];
#pragma unroll
    for (int s = 0; s < 4; ++s) {
        int k0 = 16 * s + 8 * hq;
#pragma unroll
        for (int j = 0; j < 8; ++j) v[8 * s + j] = prp[k0 + j];
    }
    float sm = 0.0f;
#pragma unroll
    for (int i = 0; i < 32; ++i) sm += v[i];
    sm += __shfl_xor(sm, 32);
    float mean = sm * (1.0f / PDIM);
    float ss = 0.0f;
#pragma unroll
    for (int i = 0; i < 32; ++i) { v[i] -= mean; ss = fmaf(v[i], v[i], ss); }
    ss += __shfl_xor(ss, 32);
    float rs = rsqrtf(ss * (1.0f / PDIM) + 1e-5f);
    bf16x8 zh[4], zl[4];
#pragma unroll
    for (int s = 0; s < 4; ++s)
#pragma unroll
        for (int j = 0; j < 8; ++j) {
            unsigned short h, l;
            split_bf(v[8 * s + j] * rs, h, l);
            zh[s][j] = (short)h; zl[s][j] = (short)l;
        }
    f32x16 acc0, acc1;
#pragma unroll
    for (int r = 0; r < 16; ++r) {
        int rr = (r & 3) + 8 * (r >> 2) + 4 * hq;
        acc0[r] = b1p[rr];
        acc1[r] = b1p[32 + rr];
    }
#pragma unroll
    for (int s = 0; s < 4; ++s) {
        int ko = 16 * s + 8 * hq;
        bf16x8 a0h = *(const bf16x8*)(w1hT + (pl << 6) + ko);
        bf16x8 a0l = *(const bf16x8*)(w1lT + (pl << 6) + ko);
        bf16x8 a1h = *(const bf16x8*)(w1hT + ((32 + pl) << 6) + ko);
        bf16x8 a1l = *(const bf16x8*)(w1lT + ((32 + pl) << 6) + ko);
        acc0 = MFMA32(a0h, zh[s], acc0);
        acc0 = MFMA32(a0h, zl[s], acc0);
        acc0 = MFMA32(a0l, zh[s], acc0);
        acc1 = MFMA32(a1h, zh[s], acc1);
        acc1 = MFMA32(a1h, zl[s], acc1);
        acc1 = MFMA32(a1l, zh[s], acc1);
    }
    float u0[16], u1[16];
    float p64 = 0.0f;
#pragma unroll
    for (int r = 0; r < 16; ++r) {
        int rr = (r & 3) + 8 * (r >> 2) + 4 * hq;
        u0[r] = gelu_erf(acc0[r]);
        u1[r] = gelu_erf(acc1[r]);
        p64 = fmaf(u0[r], w2c[rr], p64);
        p64 = fmaf(u1[r], w2c[32 + rr], p64);
    }
    p64 += __shfl_xor(p64, 32);
    float rA0[4], rB0[4], rA1[4], rB1[4];
#pragma unroll
    for (int i = 0; i < 4; ++i) {
        rA0[i] = __shfl_xor(hq ? u0[i] : u0[4 + i], 32);
        rB0[i] = __shfl_xor(hq ? u0[8 + i] : u0[12 + i], 32);
        rA1[i] = __shfl_xor(hq ? u1[i] : u1[4 + i], 32);
        rB1[i] = __shfl_xor(hq ? u1[8 + i] : u1[12 + i], 32);
    }
    bf16x8 uh[4], ul[4];
#pragma unroll
    for (int s = 0; s < 4; ++s) {
        int tt = s >> 1, q = s & 1;
#pragma unroll
        for (int i = 0; i < 4; ++i) {
            float own_f = q ? (tt ? u1[8 + i] : u0[8 + i]) : (tt ? u1[i] : u0[i]);
            float own_s = q ? (tt ? u1[12 + i] : u0[12 + i]) : (tt ? u1[4 + i] : u0[4 + i]);
            float rcv   = q ? (tt ? rB1[i] : rB0[i]) : (tt ? rA1[i] : rA0[i]);
            float f  = hq ? rcv : own_f;
            float g2 = hq ? own_s : rcv;
            unsigned short h, l;
            split_bf(f, h, l);  uh[s][i] = (short)h;     ul[s][i] = (short)l;
            split_bf(g2, h, l); uh[s][4 + i] = (short)h; ul[s][4 + i] = (short)l;
        }
    }
    f32x16 c0, c1;
#pragma unroll
    for (int r = 0; r < 16; ++r) {
        int rr = (r & 3) + 8 * (r >> 2) + 4 * hq;
        c0[r] = b2[rr];
        c1[r] = b2[32 + rr];
    }
#pragma unroll
    for (int s = 0; s < 4; ++s) {
        int ko = 16 * s + 8 * hq;
        bf16x8 a0h = *(const bf16x8*)(w2hT + (pl << 6) + ko);
        bf16x8 a0l = *(const bf16x8*)(w2lT + (pl << 6) + ko);
        bf16x8 a1h = *(const bf16x8*)(w2hT + ((32 + pl) << 6) + ko);
        bf16x8 a1l = *(const bf16x8*)(w2lT + ((32 + pl) << 6) + ko);
        c0 = MFMA32(a0h, uh[s], c0);
        c0 = MFMA32(a0h, ul[s], c0);
        c0 = MFMA32(a0l, uh[s], c0);
        c1 = MFMA32(a1h, uh[s], c1);
        c1 = MFMA32(a1h, ul[s], c1);
        c1 = MFMA32(a1l, uh[s], c1);
    }
    // stage to LDS [128][65] (stride-65 -> 2-way bank aliasing, free)
#pragma unroll
    for (int r = 0; r < 16; ++r) {
        int rr = (r & 3) + 8 * (r >> 2) + 4 * hq;
        ot[pv][rr] = c0[r];
        ot[pv][32 + rr] = c1[r];
    }
    if (hq == 0) ot[pv][64] = p64 + b2[64];
    __syncthreads();
    float4* dst = (float4*)(out + ((size_t)row * LSEQ + seg * 128) * NBINS);
    const float4* src = (const float4*)&ot[0][0];
    for (int n = t; n < 128 * NBINS / 4; n += 256) dst[n] = src[n];
}

// out = (out + out^T(1,2)) / 2, in place.  One 16x16 (l,m) tile pair per block
// (upper triangle incl diagonal); lanes run along the contiguous 65-bin axis.
__global__ void k_sym(float* __restrict__ out) {
    int u = blockIdx.x;
    int b = 0;
    if (u >= NTRI) { b = 1; u -= NTRI; }
    int lt = 0, rem = NTT;
    while (u >= rem) { u -= rem; ++lt; --rem; }
    int mt = lt + u;
    int t = threadIdx.x;
    int g = t >> 6, lane = t & 63;
    float* ob = out + (size_t)b * LSEQ * LSEQ * NBINS;
    for (int e = g; e < 256; e += 4) {
        int i = e >> 4, j = e & 15;
        if (lt == mt && j < i) continue;
        size_t ia = ((size_t)(lt * 16 + i) * LSEQ + (mt * 16 + j)) * NBINS;
        size_t ib = ((size_t)(mt * 16 + j) * LSEQ + (lt * 16 + i)) * NBINS;
        for (int k = lane; k < NBINS; k += 64) {
            float a = ob[ia + k], c = ob[ib + k];
            float vv = 0.5f * (a + c);
            ob[ia + k] = vv;
            if (ia != ib) ob[ib + k] = vv;
        }
    }
}

extern "C" void kernel_launch(void* const* d_in, const int* in_sizes, int n_in,
                              void* d_out, int out_size, void* d_ws, size_t ws_size,
                              hipStream_t stream) {
    const float* x        = (const float*)d_in[0];
    const float* rp_w     = (const float*)d_in[1];
    const float* rp_b     = (const float*)d_in[2];
    const float* pos      = (const float*)d_in[3];
    const float* pii_w    = (const float*)d_in[4];
    const float* pii_b    = (const float*)d_in[5];
    const float* pij_w    = (const float*)d_in[6];
    const float* pij_b    = (const float*)d_in[7];
    const float* rel_emb  = (const float*)d_in[8];
    const float* ln_seq_g = (const float*)d_in[9];
    const float* ln_seq_b = (const float*)d_in[10];
    const float* ln_pair_g= (const float*)d_in[11];
    const float* ln_pair_b= (const float*)d_in[12];
    const float* pb_w     = (const float*)d_in[13];
    const float* in_w     = (const float*)d_in[14];
    const float* in_b     = (const float*)d_in[15];
    const float* out_w    = (const float*)d_in[16];
    const float* out_b    = (const float*)d_in[17];
    const float* ff_ln_g  = (const float*)d_in[18];
    const float* ff_ln_b  = (const float*)d_in[19];
    const float* ff_w1    = (const float*)d_in[20];
    const float* ff_b1    = (const float*)d_in[21];
    const float* ff_w2    = (const float*)d_in[22];
    const float* ff_b2    = (const float*)d_in[23];
    const float* pu_ln_g  = (const float*)d_in[24];
    const float* pu_ln_b  = (const float*)d_in[25];
    const float* pu_w1    = (const float*)d_in[26];
    const float* pu_b1    = (const float*)d_in[27];
    const float* pu_w2    = (const float*)d_in[28];
    const float* pu_b2    = (const float*)d_in[29];
    const float* outer_w  = (const float*)d_in[30];
    const float* outer_b  = (const float*)d_in[31];
    const float* dh_ln_g  = (const float*)d_in[32];
    const float* dh_ln_b  = (const float*)d_in[33];
    const float* dh_w1    = (const float*)d_in[34];
    const float* dh_b1    = (const float*)d_in[35];
    const float* dh_w2    = (const float*)d_in[36];
    const float* dh_b2    = (const float*)d_in[37];
    float* outp = (float*)d_out;

    float* W = (float*)d_ws;
    float* h    = W;  W += BATCH * LSEQ * HD;
    float* sn   = W;  W += BATCH * LSEQ * HD;
    float* qkv  = W;  W += BATCH * LSEQ * 3 * HD;
    float* ob   = W;  W += BATCH * LSEQ * HD;
    float* mid  = W;  W += BATCH * LSEQ * 4 * HD;
    float* maskA= W;  W += LSEQ * LSEQ;
    float* maskB= W;  W += LSEQ * LSEQ;
    float* poi  = W;  W += BATCH * LSEQ * PDIM;
    float* poj  = W;  W += BATCH * LSEQ * PDIM;
    float* b1p  = W;  W += 5 * 64;
    float* w2c  = W;  W += 64;
    float* gpb  = W;  W += 3 * 64;
    float* cbv  = W;  W += 64;
    unsigned short* w1hT = (unsigned short*)W;  W += 5 * 2048;
    unsigned short* w1lT = (unsigned short*)W;  W += 5 * 2048;
    unsigned short* w2hT = (unsigned short*)W;  W += 5 * 2048;
    unsigned short* w2lT = (unsigned short*)W;  W += 5 * 2048;
    // seq-GEMM split/transposed weights (bf16 hi/lo), per-layer strides in elems
    unsigned short* qwT_h = (unsigned short*)W;  W += 4 * 196608 / 2;
    unsigned short* qwT_l = (unsigned short*)W;  W += 4 * 196608 / 2;
    unsigned short* owT_h = (unsigned short*)W;  W += 4 * 65536 / 2;
    unsigned short* owT_l = (unsigned short*)W;  W += 4 * 65536 / 2;
    unsigned short* f1T_h = (unsigned short*)W;  W += 4 * 262144 / 2;
    unsigned short* f1T_l = (unsigned short*)W;  W += 4 * 262144 / 2;
    unsigned short* f2T_h = (unsigned short*)W;  W += 4 * 262144 / 2;
    unsigned short* f2T_l = (unsigned short*)W;  W += 4 * 262144 / 2;
    float* pair = W;  W += (size_t)BATCH * LSEQ * LSEQ * PDIM;

    const int rows = BATCH * LSEQ;   // 768

    k_prep<<<5, 64, 0, stream>>>(pu_ln_g, pu_ln_b, pu_w1, pu_b1, pu_w2,
                                 dh_ln_g, dh_ln_b, dh_w1, dh_b1, dh_w2,
                                 w1hT, w1lT, w2hT, w2lT, b1p, w2c);
    k_maskprep<<<3, 64, 0, stream>>>(ln_pair_g, ln_pair_b, pb_w, gpb, cbv);
    k_split_T<<<4 * 4 * 12, 256, 0, stream>>>(in_w,  qwT_h, qwT_l, 256, 768,  4, 12, 196608, 196608);
    k_split_T<<<4 * 4 * 4,  256, 0, stream>>>(out_w, owT_h, owT_l, 256, 256,  4, 4,  65536,  65536);
    k_split_T<<<4 * 4 * 16, 256, 0, stream>>>(ff_w1, f1T_h, f1T_l, 256, 1024, 4, 16, 262144, 262144);
    k_split_T<<<4 * 16 * 4, 256, 0, stream>>>(ff_w2, f2T_h, f2T_l, 1024, 256, 16, 4, 262144, 262144);
    k_h_init<<<rows, 256, 0, stream>>>(x, rp_w, rp_b, pos, h);
    k_proj2<<<rows, 128, 0, stream>>>(h, pii_w, pij_w, pii_b, pij_b, 0, poi, poj);
    k_pair_init<<<rows, 256, 0, stream>>>(poi, poj, rel_emb, pair);
    // layer-0 mask from freshly-initialized pair (layers 1..3 fused in pair_upd)
    k_mask<<<LSEQ * LSEQ / 8, 256, 0, stream>>>(pair, ln_pair_g, ln_pair_b, pb_w, maskA);

    float* mcur = maskA;
    float* mnext = maskB;
    for (int i = 0; i < 4; ++i) {
        k_ln_seq<<<rows, 256, 0, stream>>>(h, ln_seq_g + i * HD, ln_seq_b + i * HD, sn);
        // qkv = sn @ in_w + in_b
        k_gemm<false><<<144, 256, 0, stream>>>(sn, qwT_h + i * 196608, qwT_l + i * 196608,
                                               in_b + i * 768, nullptr, qkv, 256, 768);
        k_attn<<<BATCH * NHEAD * LSEQ, 256, 0, stream>>>(qkv, mcur, ob);
        // h += ob @ out_w + out_b
        k_gemm<false><<<48, 256, 0, stream>>>(ob, owT_h + i * 65536, owT_l + i * 65536,
                                              out_b + i * 256, h, h, 256, 256);
        k_ln_seq<<<rows, 256, 0, stream>>>(h, ff_ln_g + i * HD, ff_ln_b + i * HD, sn);
        // mid = gelu(sn @ ff_w1 + b1)
        k_gemm<true><<<192, 256, 0, stream>>>(sn, f1T_h + i * 262144, f1T_l + i * 262144,
                                              ff_b1 + i * 1024, nullptr, mid, 256, 1024);
        // h += mid @ ff_w2 + b2
        k_gemm<false><<<48, 256, 0, stream>>>(mid, f2T_h + i * 262144, f2T_l + i * 262144,
                                              ff_b2 + i * 256, h, h, 1024, 256);
        // centered oi+outer_b (poi) and centered oj (poj)
        k_proj2<<<rows, 128, 0, stream>>>(h, outer_w + i * 2 * HD * PDIM,
                                          outer_w + i * 2 * HD * PDIM + HD * PDIM,
                                          outer_b + i * PDIM, nullptr, 1, poi, poj);
        if (i < 3)
            hipMemsetAsync(mnext, 0, LSEQ * LSEQ * sizeof(float), stream);
        k_pair_upd<<<rows * 3, 256, 0, stream>>>(poj, poi,
                                                 w1hT + i * 4096, w1lT + i * 4096,
                                                 b1p + i * 64,
                                                 w2hT + i * 4096, w2lT + i * 4096,
                                                 pu_b2 + i * PDIM, pair,
                                                 (i < 3) ? gpb + i * 64 : nullptr,
                                                 (i < 3) ? cbv + i : nullptr,
                                                 (i < 3) ? mnext : nullptr);
        float* tmp = mcur; mcur = mnext; mnext = tmp;
    }

    k_dist<<<rows * 3, 256, 0, stream>>>(pair, w1hT + 4 * 4096, w1lT + 4 * 4096,
                                         b1p + 4 * 64, w2hT + 4 * 4096, w2lT + 4 * 4096,
                                         w2c, dh_b2, outp);
    k_sym<<<2 * NTRI, 256, 0, stream>>>(outp);
}

// Round 2
// 1168.350 us; speedup vs baseline: 1.0993x; 1.0447x over previous
//
#include <hip/hip_runtime.h>
#include <math.h>

#define LSEQ 384
#define HD 256
#define PDIM 64
#define NHEAD 4
#define NBINS 65
#define BATCH 2
#define NTT (LSEQ / 16)
#define NTRI (NTT * (NTT + 1) / 2)

typedef __attribute__((ext_vector_type(8))) short bf16x8;
typedef __attribute__((ext_vector_type(16))) float f32x16;
#define MFMA32(a, b, c) __builtin_amdgcn_mfma_f32_32x32x16_bf16(a, b, c, 0, 0, 0)

// ---- DPP-based wave64 reductions (VALU pipe, not LDS) ----
template<int CTRL, int RMASK>
__device__ __forceinline__ float dpp_sum_step(float v) {
    int x = __builtin_amdgcn_update_dpp(0, __float_as_int(v), CTRL, RMASK, 0xf, true);
    return v + __int_as_float(x);
}
template<int CTRL, int RMASK>
__device__ __forceinline__ float dpp_max_step(float v) {
    int x = __builtin_amdgcn_update_dpp(__float_as_int(v), __float_as_int(v), CTRL, RMASK, 0xf, false);
    return fmaxf(v, __int_as_float(x));
}
__device__ __forceinline__ float wsum(float v) {
    v = dpp_sum_step<0x111, 0xf>(v);
    v = dpp_sum_step<0x112, 0xf>(v);
    v = dpp_sum_step<0x114, 0xf>(v);
    v = dpp_sum_step<0x118, 0xf>(v);
    v = dpp_sum_step<0x142, 0xa>(v);
    v = dpp_sum_step<0x143, 0xc>(v);
    return __int_as_float(__builtin_amdgcn_readlane(__float_as_int(v), 63));
}
__device__ __forceinline__ float wmax(float v) {
    v = dpp_max_step<0x111, 0xf>(v);
    v = dpp_max_step<0x112, 0xf>(v);
    v = dpp_max_step<0x114, 0xf>(v);
    v = dpp_max_step<0x118, 0xf>(v);
    v = dpp_max_step<0x142, 0xa>(v);
    v = dpp_max_step<0x143, 0xc>(v);
    return __int_as_float(__builtin_amdgcn_readlane(__float_as_int(v), 63));
}
__device__ __forceinline__ float gelu_erf(float x) {
    return 0.5f * x * (1.0f + erff(x * 0.70710678f));
}

// bf16 RNE conversion + error-compensated split: x ~= hi + lo
__device__ __forceinline__ unsigned short f2bf(float x) {
    unsigned u = __float_as_uint(x);
    unsigned r = (u + 0x7fff + ((u >> 16) & 1)) >> 16;
    return (unsigned short)r;
}
__device__ __forceinline__ float bf2f(unsigned short h) {
    return __uint_as_float(((unsigned)h) << 16);
}
__device__ __forceinline__ void split_bf(float x, unsigned short& h, unsigned short& l) {
    h = f2bf(x);
    l = f2bf(x - bf2f(h));
}

// h[b,l,:] = x[b,l,:] @ rp_w + rp_b + pos[l,:]
__global__ void k_h_init(const float* __restrict__ x, const float* __restrict__ rp_w,
                         const float* __restrict__ rp_b, const float* __restrict__ pos,
                         float* __restrict__ h) {
    __shared__ float xs[48];
    int row = blockIdx.x;            // b*L + l
    int l = row % LSEQ;
    int t = threadIdx.x;
    if (t < 48) xs[t] = x[row * 48 + t];
    __syncthreads();
    float acc = rp_b[t] + pos[l * HD + t];
#pragma unroll 8
    for (int a = 0; a < 48; ++a) acc += xs[a] * rp_w[a * HD + t];
    h[row * HD + t] = acc;
}

// pA[row,:] = h[row,:] @ wA (+ bA);  pB[row,:] = h[row,:] @ wB (+ bB)
// center!=0: subtract per-row mean (LN-mean elimination downstream)
__global__ void k_proj2(const float* __restrict__ h, const float* __restrict__ wA,
                        const float* __restrict__ wB, const float* __restrict__ bA,
                        const float* __restrict__ bB, int center,
                        float* __restrict__ pA, float* __restrict__ pB) {
    __shared__ float hs[HD];
    int row = blockIdx.x;
    int t = threadIdx.x;
    hs[t] = h[row * HD + t];
    hs[t + 128] = h[row * HD + t + 128];
    __syncthreads();
    int col = t & 63;
    const float* w = (t < 64) ? wA : wB;
    const float* bias = (t < 64) ? bA : bB;
    float acc = bias ? bias[col] : 0.0f;
#pragma unroll 8
    for (int a = 0; a < HD; ++a) acc += hs[a] * w[a * PDIM + col];
    if (center) {
        float mean = wsum(acc) * (1.0f / PDIM);
        acc -= mean;
    }
    float* p = (t < 64) ? pA : pB;
    p[row * PDIM + col] = acc;
}

// pair[b,i,j,:] = pi[b,i,:] + pj[b,j,:] + rel_emb[clip(j-i)+32,:]
// 1-wave blocks of 32 j; fused layer-0 mask epilogue (LN(pair).pbs -> atomicAdd).
__global__ void __launch_bounds__(64) k_pair_init2(
    const float* __restrict__ pi, const float* __restrict__ pj,
    const float* __restrict__ rel_emb, const float* __restrict__ gpb,
    const float* __restrict__ cbv, float* __restrict__ pair,
    float* __restrict__ mask_out) {
    __shared__ __align__(16) float pt[32][65];
    int blk = blockIdx.x;            // row*12 + seg
    int row = blk / 12, seg = blk % 12;
    int b = row / LSEQ, i = row % LSEQ;
    int t = threadIdx.x;             // 0..63
    int pl = t & 31, hq = t >> 5;
    int j0 = seg * 32;
    float piv = pi[row * 64 + t];
    const float* pjb = pj + ((size_t)b * LSEQ + j0) * 64;
#pragma unroll 8
    for (int j = 0; j < 32; ++j) {
        int r = j0 + j - i; r = r < -32 ? -32 : (r > 32 ? 32 : r); r += 32;
        pt[j][t] = piv + pjb[j * 64 + t] + rel_emb[r * 64 + t];
    }
    __syncthreads();
    // stage-out to global, coalesced float4 (element-mapped past the pad)
    float4* dst4 = (float4*)(pair + ((size_t)row * LSEQ + j0) * 64);
    for (int n = t; n < 512; n += 64) {
        int r2 = n >> 4, c4 = (n & 15) << 2;
        float4 g4 = { pt[r2][c4], pt[r2][c4 + 1], pt[r2][c4 + 2], pt[r2][c4 + 3] };
        dst4[n] = g4;
    }
    // fused layer-0 mask: dot = rsqrt(var) * sum(d * g*pbs) + sum(b*pbs)
    float vv[32];
    float sv = 0.0f;
#pragma unroll
    for (int c = 0; c < 32; ++c) { vv[c] = pt[pl][hq * 32 + c]; sv += vv[c]; }
    sv += __shfl_xor(sv, 32);
    float mean = sv * (1.0f / PDIM);
    float sd2 = 0.0f, sdg = 0.0f;
#pragma unroll
    for (int c = 0; c < 32; ++c) {
        float d = vv[c] - mean;
        sd2 = fmaf(d, d, sd2);
        sdg = fmaf(d, gpb[hq * 32 + c], sdg);
    }
    sd2 += __shfl_xor(sd2, 32);
    sdg += __shfl_xor(sdg, 32);
    float rsv = rsqrtf(sd2 * (1.0f / PDIM) + 1e-5f);
    float dot = rsv * sdg + cbv[0];
    if (hq == 0)
        atomicAdd(mask_out + i * LSEQ + j0 + pl, dot * (1.0f / (BATCH * NHEAD)));
}

// prep: fold LN g/b into W1 (b1p = b1 + bb@W1), split all pair-MLP weights into
// bf16 hi/lo, stored TRANSPOSED [out][k] for direct 16B MFMA A-frag loads.
__global__ void k_prep(const float* __restrict__ pu_ln_g, const float* __restrict__ pu_ln_b,
                       const float* __restrict__ pu_w1, const float* __restrict__ pu_b1,
                       const float* __restrict__ pu_w2,
                       const float* __restrict__ dh_ln_g, const float* __restrict__ dh_ln_b,
                       const float* __restrict__ dh_w1, const float* __restrict__ dh_b1,
                       const float* __restrict__ dh_w2,
                       unsigned short* __restrict__ w1hT, unsigned short* __restrict__ w1lT,
                       unsigned short* __restrict__ w2hT, unsigned short* __restrict__ w2lT,
                       float* __restrict__ b1p, float* __restrict__ w2c) {
    int i = blockIdx.x;              // 0..4
    int c = threadIdx.x;             // 0..63 = output row of transposed arrays
    const float *g, *bb, *w1, *b1, *w2;
    int w2s;
    if (i < 4) { g = pu_ln_g + i * 64; bb = pu_ln_b + i * 64; w1 = pu_w1 + i * 4096;
                 b1 = pu_b1 + i * 64; w2 = pu_w2 + i * 4096; w2s = 64; }
    else       { g = dh_ln_g; bb = dh_ln_b; w1 = dh_w1; b1 = dh_b1; w2 = dh_w2; w2s = 65; }
    float accb = b1[c];
    for (int k = 0; k < 64; ++k) {
        float wv = w1[k * 64 + c];
        accb += bb[k] * wv;
        unsigned short h, l;
        split_bf(g[k] * wv, h, l);                 // W1'[k][c] stored at [c][k]
        w1hT[i * 4096 + c * 64 + k] = h;
        w1lT[i * 4096 + c * 64 + k] = l;
        split_bf(w2[k * w2s + c], h, l);           // W2[k][c] stored at [c][k]
        w2hT[i * 4096 + c * 64 + k] = h;
        w2lT[i * 4096 + c * 64 + k] = l;
    }
    b1p[i * 64 + c] = accb;
    if (i == 4) w2c[c] = dh_w2[c * 65 + 64];
}

// prep for fused mask: gp[li][c] = ln_pair_g[li][c] * pbs[c],
// cb[li] = sum_c ln_pair_b[li][c]*pbs[c], pbs[c] = sum_h pb_w[li][c][h]. li=0..3.
__global__ void k_maskprep(const float* __restrict__ g, const float* __restrict__ bb,
                           const float* __restrict__ pbw, float* __restrict__ gp,
                           float* __restrict__ cb) {
    int li = blockIdx.x;             // layer 0..3
    int c = threadIdx.x;             // 0..63 (one wave)
    const float* pw = pbw + li * PDIM * NHEAD;
    float pbs = pw[c * 4] + pw[c * 4 + 1] + pw[c * 4 + 2] + pw[c * 4 + 3];
    gp[li * 64 + c] = g[li * 64 + c] * pbs;
    float s = wsum(bb[li * 64 + c] * pbs);
    if (c == 0) cb[li] = s;
}

// prep: split+transpose seq weights to bf16 hi/lo [n][k] via 64x64 LDS tiles.
// src: [K][N] row-major, per-layer stride sstride; dst: [N][K], stride dstride.
__global__ void k_split_T(const float* __restrict__ src, unsigned short* __restrict__ dh,
                          unsigned short* __restrict__ dl, int K, int N,
                          int tiles_k, int tiles_n, size_t sstride, size_t dstride) {
    __shared__ float lds[64][65];
    int bid = blockIdx.x;
    int tpl = tiles_k * tiles_n;
    int layer = bid / tpl;
    int rest = bid % tpl;
    int kt = rest / tiles_n, nt = rest % tiles_n;
    const float* s = src + layer * sstride;
    int t = threadIdx.x, c = t & 63, r0 = t >> 6;
    for (int r = r0; r < 64; r += 4)
        lds[r][c] = s[(size_t)(kt * 64 + r) * N + nt * 64 + c];
    __syncthreads();
    unsigned short* oh = dh + layer * dstride;
    unsigned short* ol = dl + layer * dstride;
    for (int r = r0; r < 64; r += 4) {
        float v = lds[c][r];                       // src[kt*64+c][nt*64+r]
        unsigned short h, l;
        split_bf(v, h, l);
        size_t o = (size_t)(nt * 64 + r) * K + kt * 64 + c;
        oh[o] = h;
        ol[o] = l;
    }
}

// ============ generic MFMA seq GEMM ============
// OUT[m][n] = epi( X[m][:]@W + bias[n] + (R?R[m][n]:0) ), M=768 rows.
// W pre-split bf16 hi/lo transposed [n][k]. Wave = 32x32 tile, block = 4 waves.
template<bool GELU>
__global__ void __launch_bounds__(256) k_gemm(
    const float* __restrict__ X, const unsigned short* __restrict__ wTh,
    const unsigned short* __restrict__ wTl, const float* __restrict__ bias,
    const float* __restrict__ R, float* __restrict__ OUT, int K, int N) {
    int idx = blockIdx.x * 4 + (threadIdx.x >> 6);
    int lane = threadIdx.x & 63;
    int pl = lane & 31, hq = lane >> 5;
    int ntiles = N >> 5;
    int mt = idx / ntiles, nt = idx % ntiles;
    const float* xr = X + (size_t)(mt * 32 + pl) * K + 8 * hq;
    const unsigned short* bh = wTh + (size_t)(nt * 32 + pl) * K + 8 * hq;
    const unsigned short* bl = wTl + (size_t)(nt * 32 + pl) * K + 8 * hq;
    int n = nt * 32 + pl;
    float bv = bias[n];
    f32x16 acc;
#pragma unroll
    for (int r = 0; r < 16; ++r) {
        int mr = mt * 32 + (r & 3) + 8 * (r >> 2) + 4 * hq;
        acc[r] = bv + (R ? R[(size_t)mr * N + n] : 0.0f);
    }
#pragma unroll 4
    for (int s = 0; s < K; s += 16) {
        bf16x8 ah, al;
#pragma unroll
        for (int j = 0; j < 8; ++j) {
            unsigned short h, l;
            split_bf(xr[s + j], h, l);
            ah[j] = (short)h; al[j] = (short)l;
        }
        bf16x8 bhv = *(const bf16x8*)(bh + s);
        bf16x8 blv = *(const bf16x8*)(bl + s);
        acc = MFMA32(ah, bhv, acc);
        acc = MFMA32(al, bhv, acc);
        acc = MFMA32(ah, blv, acc);
    }
#pragma unroll
    for (int r = 0; r < 16; ++r) {
        int mr = mt * 32 + (r & 3) + 8 * (r >> 2) + 4 * hq;
        float v = acc[r];
        OUT[(size_t)mr * N + n] = GELU ? gelu_erf(v) : v;
    }
}

// seq layernorm: one row per block
__global__ void k_ln_seq(const float* __restrict__ h, const float* __restrict__ g,
                         const float* __restrict__ b, float* __restrict__ out) {
    __shared__ float red[8];
    int row = blockIdx.x;
    int t = threadIdx.x;
    int w = t >> 6, lane = t & 63;
    float v = h[row * HD + t];
    float s = wsum(v);
    if (lane == 0) red[w] = s;
    __syncthreads();
    float mean = (red[0] + red[1] + red[2] + red[3]) * (1.0f / HD);
    float d = v - mean;
    float q = wsum(d * d);
    if (lane == 0) red[4 + w] = q;
    __syncthreads();
    float var = (red[4] + red[5] + red[6] + red[7]) * (1.0f / HD);
    out[row * HD + t] = d * rsqrtf(var + 1e-5f) * g[t] + b[t];
}

// attention for one (b, nh, l) per block
__global__ void k_attn(const float* __restrict__ qkv, const float* __restrict__ mask,
                       float* __restrict__ o) {
    __shared__ __align__(16) float qs[64];
    __shared__ float sc[LSEQ];
    __shared__ float red[8];
    __shared__ float op[4][64];
    int bid = blockIdx.x;
    int l = bid % LSEQ;
    int nh = (bid / LSEQ) & 3;
    int b = bid / (LSEQ * NHEAD);
    int t = threadIdx.x;
    int w = t >> 6, lane = t & 63;
    const float* qbase = qkv + ((size_t)(b * LSEQ + l)) * 768 + nh * 64;
    if (t < 64) qs[t] = qbase[t];
    __syncthreads();
    float lmax = -1e30f;
    float myv[2];
#pragma unroll
    for (int it = 0; it < 2; ++it) {
        int m = t + it * 256;
        if (m < LSEQ) {
            const float* kb = qkv + ((size_t)(b * LSEQ + m)) * 768 + 256 + nh * 64;
            const float4* k4 = (const float4*)kb;
            const float4* q4 = (const float4*)qs;
            float acc = 0.0f;
#pragma unroll
            for (int a = 0; a < 16; ++a) {
                float4 kv = k4[a], qv = q4[a];
                acc += qv.x * kv.x + qv.y * kv.y + qv.z * kv.z + qv.w * kv.w;
            }
            float s = acc * 0.125f + mask[l * LSEQ + m];
            myv[it] = s;
            lmax = fmaxf(lmax, s);
        } else myv[it] = -1e30f;
    }
    float wm = wmax(lmax);
    if (lane == 0) red[w] = wm;
    __syncthreads();
    float gmax = fmaxf(fmaxf(red[0], red[1]), fmaxf(red[2], red[3]));
    float lsum = 0.0f;
#pragma unroll
    for (int it = 0; it < 2; ++it) {
        int m = t + it * 256;
        if (m < LSEQ) {
            float e = expf(myv[it] - gmax);
            sc[m] = e;
            lsum += e;
        }
    }
    float ws = wsum(lsum);
    if (lane == 0) red[4 + w] = ws;
    __syncthreads();
    float inv = 1.0f / (red[4] + red[5] + red[6] + red[7]);
    int d = t & 63, gq = t >> 6;
    float part = 0.0f;
    for (int m = gq * 96; m < (gq + 1) * 96; ++m)
        part += sc[m] * qkv[((size_t)(b * LSEQ + m)) * 768 + 512 + nh * 64 + d];
    op[gq][d] = part;
    __syncthreads();
    if (t < 64) {
        float ov = (op[0][t] + op[1][t] + op[2][t] + op[3][t]) * inv;
        o[((size_t)(b * LSEQ + l)) * HD + nh * 64 + t] = ov;
    }
}

// ============ MFMA pair-update, 1-wave blocks (+ fused mask / dist head) ============
// Block = 1 wave = 32 j-values; LDS 8.3KB -> high residency for latency hiding.
// !DIST: pair += MLP(LN(outer)); optional fused next-layer mask (atomicAdd).
// DIST (last layer): final pair stays in registers/LDS, dist-head MLP applied
// directly, logits written; pair is never stored to HBM.
template<bool DIST>
__global__ void __launch_bounds__(64) k_pair_upd(
    const float* __restrict__ ojc,   // centered oj         (B,L,64)
    const float* __restrict__ oic,   // centered oi+outer_b (B,L,64)
    const unsigned short* __restrict__ w1hT, const unsigned short* __restrict__ w1lT,
    const float* __restrict__ b1p,
    const unsigned short* __restrict__ w2hT, const unsigned short* __restrict__ w2lT,
    const float* __restrict__ b2, float* __restrict__ pair,
    const float* __restrict__ gpb, const float* __restrict__ cbv,
    float* __restrict__ mask_out,
    const unsigned short* __restrict__ dw1h, const unsigned short* __restrict__ dw1l,
    const float* __restrict__ db1p,
    const unsigned short* __restrict__ dw2h, const unsigned short* __restrict__ dw2l,
    const float* __restrict__ w2c, const float* __restrict__ db2,
    float* __restrict__ outg) {
    __shared__ __align__(16) float pt[32][65];
    int blk = blockIdx.x;            // row*12 + seg
    int row = blk / 12, seg = blk % 12;
    int b = row / LSEQ;
    int t = threadIdx.x;             // 0..63
    int pl = t & 31, hq = t >> 5;
    int p = seg * 32 + pl;           // j index within pair row
    const float* ojr = ojc + ((size_t)b * LSEQ + p) * 64;
    const float* oir = oic + (size_t)row * 64;
    float* prblk = pair + ((size_t)row * LSEQ + seg * 32) * 64;

    // stage-in: contiguous 8KB pair region -> LDS (residual read)
    const float4* src4 = (const float4*)prblk;
    for (int n = t; n < 512; n += 64) {
        float4 g4 = src4[n];
        int r2 = n >> 4, ch = (n & 15) << 2;
        pt[r2][ch] = g4.x; pt[r2][ch + 1] = g4.y;
        pt[r2][ch + 2] = g4.z; pt[r2][ch + 3] = g4.w;
    }

    float v[32];
#pragma unroll
    for (int s = 0; s < 4; ++s) {
        int k0 = 16 * s + 8 * hq;
#pragma unroll
        for (int j = 0; j < 8; ++j) v[8 * s + j] = ojr[k0 + j] + oir[k0 + j];
    }
    float ss = 0.0f;
#pragma unroll
    for (int i = 0; i < 32; ++i) ss = fmaf(v[i], v[i], ss);
    ss += __shfl_xor(ss, 32);
    float rs = rsqrtf(ss * (1.0f / PDIM) + 1e-5f);
    bf16x8 zh[4], zl[4];
#pragma unroll
    for (int s = 0; s < 4; ++s)
#pragma unroll
        for (int j = 0; j < 8; ++j) {
            unsigned short h, l;
            split_bf(v[8 * s + j] * rs, h, l);
            zh[s][j] = (short)h; zl[s][j] = (short)l;
        }

    f32x16 acc0, acc1;
#pragma unroll
    for (int r = 0; r < 16; ++r) {
        int rr = (r & 3) + 8 * (r >> 2) + 4 * hq;
        acc0[r] = b1p[rr];
        acc1[r] = b1p[32 + rr];
    }
#pragma unroll
    for (int s = 0; s < 4; ++s) {
        int ko = 16 * s + 8 * hq;
        bf16x8 a0h = *(const bf16x8*)(w1hT + (pl << 6) + ko);
        bf16x8 a0l = *(const bf16x8*)(w1lT + (pl << 6) + ko);
        bf16x8 a1h = *(const bf16x8*)(w1hT + ((32 + pl) << 6) + ko);
        bf16x8 a1l = *(const bf16x8*)(w1lT + ((32 + pl) << 6) + ko);
        acc0 = MFMA32(a0h, zh[s], acc0);
        acc0 = MFMA32(a0h, zl[s], acc0);
        acc0 = MFMA32(a0l, zh[s], acc0);
        acc1 = MFMA32(a1h, zh[s], acc1);
        acc1 = MFMA32(a1h, zl[s], acc1);
        acc1 = MFMA32(a1l, zh[s], acc1);
    }
    float u0[16], u1[16];
#pragma unroll
    for (int r = 0; r < 16; ++r) { u0[r] = gelu_erf(acc0[r]); u1[r] = gelu_erf(acc1[r]); }

    float rA0[4], rB0[4], rA1[4], rB1[4];
#pragma unroll
    for (int i = 0; i < 4; ++i) {
        rA0[i] = __shfl_xor(hq ? u0[i] : u0[4 + i], 32);
        rB0[i] = __shfl_xor(hq ? u0[8 + i] : u0[12 + i], 32);
        rA1[i] = __shfl_xor(hq ? u1[i] : u1[4 + i], 32);
        rB1[i] = __shfl_xor(hq ? u1[8 + i] : u1[12 + i], 32);
    }
    bf16x8 uh[4], ul[4];
#pragma unroll
    for (int s = 0; s < 4; ++s) {
        int tt = s >> 1, q = s & 1;
#pragma unroll
        for (int i = 0; i < 4; ++i) {
            float own_f = q ? (tt ? u1[8 + i] : u0[8 + i]) : (tt ? u1[i] : u0[i]);
            float own_s = q ? (tt ? u1[12 + i] : u0[12 + i]) : (tt ? u1[4 + i] : u0[4 + i]);
            float rcv   = q ? (tt ? rB1[i] : rB0[i]) : (tt ? rA1[i] : rA0[i]);
            float f  = hq ? rcv : own_f;
            float g2 = hq ? own_s : rcv;
            unsigned short h, l;
            split_bf(f, h, l);  uh[s][i] = (short)h;     ul[s][i] = (short)l;
            split_bf(g2, h, l); uh[s][4 + i] = (short)h; ul[s][4 + i] = (short)l;
        }
    }

    __syncthreads();  // stage-in complete before residual reads
    f32x16 c0, c1;
#pragma unroll
    for (int r = 0; r < 16; ++r) {
        int rr = (r & 3) + 8 * (r >> 2) + 4 * hq;
        c0[r] = b2[rr] + pt[pl][rr];
        c1[r] = b2[32 + rr] + pt[pl][32 + rr];
    }
#pragma unroll
    for (int s = 0; s < 4; ++s) {
        int ko = 16 * s + 8 * hq;
        bf16x8 a0h = *(const bf16x8*)(w2hT + (pl << 6) + ko);
        bf16x8 a0l = *(const bf16x8*)(w2lT + (pl << 6) + ko);
        bf16x8 a1h = *(const bf16x8*)(w2hT + ((32 + pl) << 6) + ko);
        bf16x8 a1l = *(const bf16x8*)(w2lT + ((32 + pl) << 6) + ko);
        c0 = MFMA32(a0h, uh[s], c0);
        c0 = MFMA32(a0h, ul[s], c0);
        c0 = MFMA32(a0l, uh[s], c0);
        c1 = MFMA32(a1h, uh[s], c1);
        c1 = MFMA32(a1h, ul[s], c1);
        c1 = MFMA32(a1l, uh[s], c1);
    }

    if constexpr (!DIST) {
        // write final pair values back to LDS (same slots this lane read; no race)
#pragma unroll
        for (int r = 0; r < 16; ++r) {
            int rr = (r & 3) + 8 * (r >> 2) + 4 * hq;
            pt[pl][rr] = c0[r];
            pt[pl][32 + rr] = c1[r];
        }
        // fused mask for next layer: LN(final pair) . pbsum, mean over b via atomics
        if (mask_out) {
            float sv = 0.0f;
#pragma unroll
            for (int r = 0; r < 16; ++r) sv += c0[r] + c1[r];
            sv += __shfl_xor(sv, 32);
            float mean = sv * (1.0f / PDIM);
            float sd2 = 0.0f, sdg = 0.0f;
#pragma unroll 4
            for (int r = 0; r < 16; ++r) {
                int rr = (r & 3) + 8 * (r >> 2) + 4 * hq;
                float d0 = c0[r] - mean, d1 = c1[r] - mean;
                sd2 = fmaf(d0, d0, sd2);
                sd2 = fmaf(d1, d1, sd2);
                sdg = fmaf(d0, gpb[rr], sdg);
                sdg = fmaf(d1, gpb[32 + rr], sdg);
            }
            sd2 += __shfl_xor(sd2, 32);
            sdg += __shfl_xor(sdg, 32);
            float rsv = rsqrtf(sd2 * (1.0f / PDIM) + 1e-5f);
            float dot = rsv * sdg + cbv[0];
            if (hq == 0)
                atomicAdd(mask_out + (row % LSEQ) * LSEQ + p, dot * (1.0f / (BATCH * NHEAD)));
        }
        __syncthreads();
        // stage-out: LDS -> contiguous coalesced float4 stores
        float4* dst4 = (float4*)prblk;
        for (int n = t; n < 512; n += 64) {
            int r2 = n >> 4, ch = (n & 15) << 2;
            float4 g4 = { pt[r2][ch], pt[r2][ch + 1], pt[r2][ch + 2], pt[r2][ch + 3] };
            dst4[n] = g4;
        }
    } else {
        // ---- fused distogram head: final pair lives only in regs/LDS ----
        // route fragment layout -> k-order via LDS
#pragma unroll
        for (int r = 0; r < 16; ++r) {
            int rr = (r & 3) + 8 * (r >> 2) + 4 * hq;
            pt[pl][rr] = c0[r];
            pt[pl][32 + rr] = c1[r];
        }
        __syncthreads();
        float v2[32];
#pragma unroll
        for (int s = 0; s < 4; ++s) {
            int k0 = 16 * s + 8 * hq;
#pragma unroll
            for (int j = 0; j < 8; ++j) v2[8 * s + j] = pt[pl][k0 + j];
        }
        float sm = 0.0f;
#pragma unroll
        for (int i = 0; i < 32; ++i) sm += v2[i];
        sm += __shfl_xor(sm, 32);
        float mean = sm * (1.0f / PDIM);
        float ss2 = 0.0f;
#pragma unroll
        for (int i = 0; i < 32; ++i) { v2[i] -= mean; ss2 = fmaf(v2[i], v2[i], ss2); }
        ss2 += __shfl_xor(ss2, 32);
        float rs2 = rsqrtf(ss2 * (1.0f / PDIM) + 1e-5f);
#pragma unroll
        for (int s = 0; s < 4; ++s)
#pragma unroll
            for (int j = 0; j < 8; ++j) {
                unsigned short h, l;
                split_bf(v2[8 * s + j] * rs2, h, l);
                zh[s][j] = (short)h; zl[s][j] = (short)l;
            }
#pragma unroll
        for (int r = 0; r < 16; ++r) {
            int rr = (r & 3) + 8 * (r >> 2) + 4 * hq;
            acc0[r] = db1p[rr];
            acc1[r] = db1p[32 + rr];
        }
#pragma unroll
        for (int s = 0; s < 4; ++s) {
            int ko = 16 * s + 8 * hq;
            bf16x8 a0h = *(const bf16x8*)(dw1h + (pl << 6) + ko);
            bf16x8 a0l = *(const bf16x8*)(dw1l + (pl << 6) + ko);
            bf16x8 a1h = *(const bf16x8*)(dw1h + ((32 + pl) << 6) + ko);
            bf16x8 a1l = *(const bf16x8*)(dw1l + ((32 + pl) << 6) + ko);
            acc0 = MFMA32(a0h, zh[s], acc0);
            acc0 = MFMA32(a0h, zl[s], acc0);
            acc0 = MFMA32(a0l, zh[s], acc0);
            acc1 = MFMA32(a1h, zh[s], acc1);
            acc1 = MFMA32(a1h, zl[s], acc1);
            acc1 = MFMA32(a1l, zh[s], acc1);
        }
        float p64 = 0.0f;
#pragma unroll
        for (int r = 0; r < 16; ++r) {
            int rr = (r & 3) + 8 * (r >> 2) + 4 * hq;
            u0[r] = gelu_erf(acc0[r]);
            u1[r] = gelu_erf(acc1[r]);
            p64 = fmaf(u0[r], w2c[rr], p64);
            p64 = fmaf(u1[r], w2c[32 + rr], p64);
        }
        p64 += __shfl_xor(p64, 32);
#pragma unroll
        for (int i = 0; i < 4; ++i) {
            rA0[i] = __shfl_xor(hq ? u0[i] : u0[4 + i], 32);
            rB0[i] = __shfl_xor(hq ? u0[8 + i] : u0[12 + i], 32);
            rA1[i] = __shfl_xor(hq ? u1[i] : u1[4 + i], 32);
            rB1[i] = __shfl_xor(hq ? u1[8 + i] : u1[12 + i], 32);
        }
#pragma unroll
        for (int s = 0; s < 4; ++s) {
            int tt = s >> 1, q = s & 1;
#pragma unroll
            for (int i = 0; i < 4; ++i) {
                float own_f = q ? (tt ? u1[8 + i] : u0[8 + i]) : (tt ? u1[i] : u0[i]);
                float own_s = q ? (tt ? u1[12 + i] : u0[12 + i]) : (tt ? u1[4 + i] : u0[4 + i]);
                float rcv   = q ? (tt ? rB1[i] : rB0[i]) : (tt ? rA1[i] : rA0[i]);
                float f  = hq ? rcv : own_f;
                float g2 = hq ? own_s : rcv;
                unsigned short h, l;
                split_bf(f, h, l);  uh[s][i] = (short)h;     ul[s][i] = (short)l;
                split_bf(g2, h, l); uh[s][4 + i] = (short)h; ul[s][4 + i] = (short)l;
            }
        }
#pragma unroll
        for (int r = 0; r < 16; ++r) {
            int rr = (r & 3) + 8 * (r >> 2) + 4 * hq;
            c0[r] = db2[rr];
            c1[r] = db2[32 + rr];
        }
#pragma unroll
        for (int s = 0; s < 4; ++s) {
            int ko = 16 * s + 8 * hq;
            bf16x8 a0h = *(const bf16x8*)(dw2h + (pl << 6) + ko);
            bf16x8 a0l = *(const bf16x8*)(dw2l + (pl << 6) + ko);
            bf16x8 a1h = *(const bf16x8*)(dw2h + ((32 + pl) << 6) + ko);
            bf16x8 a1l = *(const bf16x8*)(dw2l + ((32 + pl) << 6) + ko);
            c0 = MFMA32(a0h, uh[s], c0);
            c0 = MFMA32(a0h, ul[s], c0);
            c0 = MFMA32(a0l, uh[s], c0);
            c1 = MFMA32(a1h, uh[s], c1);
            c1 = MFMA32(a1h, ul[s], c1);
            c1 = MFMA32(a1l, uh[s], c1);
        }
        __syncthreads();   // prior k-order reads done before pt reuse as out tile
#pragma unroll
        for (int r = 0; r < 16; ++r) {
            int rr = (r & 3) + 8 * (r >> 2) + 4 * hq;
            pt[pl][rr] = c0[r];
            pt[pl][32 + rr] = c1[r];
        }
        if (hq == 0) pt[pl][64] = p64 + db2[64];
        __syncthreads();
        // 32 rows x 65 bins = exactly pt's linearization -> coalesced float4 copy
        float4* dst = (float4*)(outg + ((size_t)row * LSEQ + seg * 32) * NBINS);
        const float4* srcl = (const float4*)&pt[0][0];
        for (int n = t; n < 520; n += 64) dst[n] = srcl[n];
    }
}

// out = (out + out^T(1,2)) / 2, in place.  One 16x16 (l,m) tile pair per block
// (upper triangle incl diagonal); lanes run along the contiguous 65-bin axis.
__global__ void k_sym(float* __restrict__ out) {
    int u = blockIdx.x;
    int b = 0;
    if (u >= NTRI) { b = 1; u -= NTRI; }
    int lt = 0, rem = NTT;
    while (u >= rem) { u -= rem; ++lt; --rem; }
    int mt = lt + u;
    int t = threadIdx.x;
    int g = t >> 6, lane = t & 63;
    float* ob = out + (size_t)b * LSEQ * LSEQ * NBINS;
    for (int e = g; e < 256; e += 4) {
        int i = e >> 4, j = e & 15;
        if (lt == mt && j < i) continue;
        size_t ia = ((size_t)(lt * 16 + i) * LSEQ + (mt * 16 + j)) * NBINS;
        size_t ib = ((size_t)(mt * 16 + j) * LSEQ + (lt * 16 + i)) * NBINS;
        for (int k = lane; k < NBINS; k += 64) {
            float a = ob[ia + k], c = ob[ib + k];
            float vv = 0.5f * (a + c);
            ob[ia + k] = vv;
            if (ia != ib) ob[ib + k] = vv;
        }
    }
}

extern "C" void kernel_launch(void* const* d_in, const int* in_sizes, int n_in,
                              void* d_out, int out_size, void* d_ws, size_t ws_size,
                              hipStream_t stream) {
    const float* x        = (const float*)d_in[0];
    const float* rp_w     = (const float*)d_in[1];
    const float* rp_b     = (const float*)d_in[2];
    const float* pos      = (const float*)d_in[3];
    const float* pii_w    = (const float*)d_in[4];
    const float* pii_b    = (const float*)d_in[5];
    const float* pij_w    = (const float*)d_in[6];
    const float* pij_b    = (const float*)d_in[7];
    const float* rel_emb  = (const float*)d_in[8];
    const float* ln_seq_g = (const float*)d_in[9];
    const float* ln_seq_b = (const float*)d_in[10];
    const float* ln_pair_g= (const float*)d_in[11];
    const float* ln_pair_b= (const float*)d_in[12];
    const float* pb_w     = (const float*)d_in[13];
    const float* in_w     = (const float*)d_in[14];
    const float* in_b     = (const float*)d_in[15];
    const float* out_w    = (const float*)d_in[16];
    const float* out_b    = (const float*)d_in[17];
    const float* ff_ln_g  = (const float*)d_in[18];
    const float* ff_ln_b  = (const float*)d_in[19];
    const float* ff_w1    = (const float*)d_in[20];
    const float* ff_b1    = (const float*)d_in[21];
    const float* ff_w2    = (const float*)d_in[22];
    const float* ff_b2    = (const float*)d_in[23];
    const float* pu_ln_g  = (const float*)d_in[24];
    const float* pu_ln_b  = (const float*)d_in[25];
    const float* pu_w1    = (const float*)d_in[26];
    const float* pu_b1    = (const float*)d_in[27];
    const float* pu_w2    = (const float*)d_in[28];
    const float* pu_b2    = (const float*)d_in[29];
    const float* outer_w  = (const float*)d_in[30];
    const float* outer_b  = (const float*)d_in[31];
    const float* dh_ln_g  = (const float*)d_in[32];
    const float* dh_ln_b  = (const float*)d_in[33];
    const float* dh_w1    = (const float*)d_in[34];
    const float* dh_b1    = (const float*)d_in[35];
    const float* dh_w2    = (const float*)d_in[36];
    const float* dh_b2    = (const float*)d_in[37];
    float* outp = (float*)d_out;

    float* W = (float*)d_ws;
    float* h    = W;  W += BATCH * LSEQ * HD;
    float* sn   = W;  W += BATCH * LSEQ * HD;
    float* qkv  = W;  W += BATCH * LSEQ * 3 * HD;
    float* ob   = W;  W += BATCH * LSEQ * HD;
    float* mid  = W;  W += BATCH * LSEQ * 4 * HD;
    float* maskA= W;  W += LSEQ * LSEQ;
    float* maskB= W;  W += LSEQ * LSEQ;
    float* poi  = W;  W += BATCH * LSEQ * PDIM;
    float* poj  = W;  W += BATCH * LSEQ * PDIM;
    float* b1p  = W;  W += 5 * 64;
    float* w2c  = W;  W += 64;
    float* gpb  = W;  W += 4 * 64;
    float* cbv  = W;  W += 64;
    unsigned short* w1hT = (unsigned short*)W;  W += 5 * 2048;
    unsigned short* w1lT = (unsigned short*)W;  W += 5 * 2048;
    unsigned short* w2hT = (unsigned short*)W;  W += 5 * 2048;
    unsigned short* w2lT = (unsigned short*)W;  W += 5 * 2048;
    // seq-GEMM split/transposed weights (bf16 hi/lo), per-layer strides in elems
    unsigned short* qwT_h = (unsigned short*)W;  W += 4 * 196608 / 2;
    unsigned short* qwT_l = (unsigned short*)W;  W += 4 * 196608 / 2;
    unsigned short* owT_h = (unsigned short*)W;  W += 4 * 65536 / 2;
    unsigned short* owT_l = (unsigned short*)W;  W += 4 * 65536 / 2;
    unsigned short* f1T_h = (unsigned short*)W;  W += 4 * 262144 / 2;
    unsigned short* f1T_l = (unsigned short*)W;  W += 4 * 262144 / 2;
    unsigned short* f2T_h = (unsigned short*)W;  W += 4 * 262144 / 2;
    unsigned short* f2T_l = (unsigned short*)W;  W += 4 * 262144 / 2;
    float* pair = W;  W += (size_t)BATCH * LSEQ * LSEQ * PDIM;

    const int rows = BATCH * LSEQ;   // 768

    k_prep<<<5, 64, 0, stream>>>(pu_ln_g, pu_ln_b, pu_w1, pu_b1, pu_w2,
                                 dh_ln_g, dh_ln_b, dh_w1, dh_b1, dh_w2,
                                 w1hT, w1lT, w2hT, w2lT, b1p, w2c);
    k_maskprep<<<4, 64, 0, stream>>>(ln_pair_g, ln_pair_b, pb_w, gpb, cbv);
    k_split_T<<<4 * 4 * 12, 256, 0, stream>>>(in_w,  qwT_h, qwT_l, 256, 768,  4, 12, 196608, 196608);
    k_split_T<<<4 * 4 * 4,  256, 0, stream>>>(out_w, owT_h, owT_l, 256, 256,  4, 4,  65536,  65536);
    k_split_T<<<4 * 4 * 16, 256, 0, stream>>>(ff_w1, f1T_h, f1T_l, 256, 1024, 4, 16, 262144, 262144);
    k_split_T<<<4 * 16 * 4, 256, 0, stream>>>(ff_w2, f2T_h, f2T_l, 1024, 256, 16, 4, 262144, 262144);
    k_h_init<<<rows, 256, 0, stream>>>(x, rp_w, rp_b, pos, h);
    k_proj2<<<rows, 128, 0, stream>>>(h, pii_w, pij_w, pii_b, pij_b, 0, poi, poj);
    hipMemsetAsync(maskA, 0, LSEQ * LSEQ * sizeof(float), stream);
    // pair init with fused layer-0 mask
    k_pair_init2<<<rows * 12, 64, 0, stream>>>(poi, poj, rel_emb, gpb, cbv, pair, maskA);

    float* mcur = maskA;
    float* mnext = maskB;
    for (int i = 0; i < 4; ++i) {
        k_ln_seq<<<rows, 256, 0, stream>>>(h, ln_seq_g + i * HD, ln_seq_b + i * HD, sn);
        // qkv = sn @ in_w + in_b
        k_gemm<false><<<144, 256, 0, stream>>>(sn, qwT_h + i * 196608, qwT_l + i * 196608,
                                               in_b + i * 768, nullptr, qkv, 256, 768);
        k_attn<<<BATCH * NHEAD * LSEQ, 256, 0, stream>>>(qkv, mcur, ob);
        // h += ob @ out_w + out_b
        k_gemm<false><<<48, 256, 0, stream>>>(ob, owT_h + i * 65536, owT_l + i * 65536,
                                              out_b + i * 256, h, h, 256, 256);
        k_ln_seq<<<rows, 256, 0, stream>>>(h, ff_ln_g + i * HD, ff_ln_b + i * HD, sn);
        // mid = gelu(sn @ ff_w1 + b1)
        k_gemm<true><<<192, 256, 0, stream>>>(sn, f1T_h + i * 262144, f1T_l + i * 262144,
                                              ff_b1 + i * 1024, nullptr, mid, 256, 1024);
        // h += mid @ ff_w2 + b2
        k_gemm<false><<<48, 256, 0, stream>>>(mid, f2T_h + i * 262144, f2T_l + i * 262144,
                                              ff_b2 + i * 256, h, h, 1024, 256);
        // centered oi+outer_b (poi) and centered oj (poj)
        k_proj2<<<rows, 128, 0, stream>>>(h, outer_w + i * 2 * HD * PDIM,
                                          outer_w + i * 2 * HD * PDIM + HD * PDIM,
                                          outer_b + i * PDIM, nullptr, 1, poi, poj);
        if (i < 3) {
            hipMemsetAsync(mnext, 0, LSEQ * LSEQ * sizeof(float), stream);
            k_pair_upd<false><<<rows * 12, 64, 0, stream>>>(
                poj, poi,
                w1hT + i * 4096, w1lT + i * 4096, b1p + i * 64,
                w2hT + i * 4096, w2lT + i * 4096, pu_b2 + i * PDIM, pair,
                gpb + (i + 1) * 64, cbv + (i + 1), mnext,
                nullptr, nullptr, nullptr, nullptr, nullptr, nullptr, nullptr, nullptr);
            float* tmp = mcur; mcur = mnext; mnext = tmp;
        } else {
            // last layer: pair update fused with distogram head; pair never stored
            k_pair_upd<true><<<rows * 12, 64, 0, stream>>>(
                poj, poi,
                w1hT + 3 * 4096, w1lT + 3 * 4096, b1p + 3 * 64,
                w2hT + 3 * 4096, w2lT + 3 * 4096, pu_b2 + 3 * PDIM, pair,
                nullptr, nullptr, nullptr,
                w1hT + 4 * 4096, w1lT + 4 * 4096, b1p + 4 * 64,
                w2hT + 4 * 4096, w2lT + 4 * 4096, w2c, dh_b2, outp);
        }
    }

    k_sym<<<2 * NTRI, 256, 0, stream>>>(outp);
}

// Round 3
// 1116.698 us; speedup vs baseline: 1.1501x; 1.0463x over previous
//
#include <hip/hip_runtime.h>
#include <math.h>

#define LSEQ 384
#define HD 256
#define PDIM 64
#define NHEAD 4
#define NBINS 65
#define BATCH 2
#define NTT (LSEQ / 16)
#define NTRI (NTT * (NTT + 1) / 2)

typedef __attribute__((ext_vector_type(8))) short bf16x8;
typedef __attribute__((ext_vector_type(16))) float f32x16;
typedef __attribute__((ext_vector_type(4))) float f32x4;
typedef __attribute__((ext_vector_type(4))) unsigned u32x4;
typedef __attribute__((ext_vector_type(4))) short s16x4;
#define MFMA32(a, b, c) __builtin_amdgcn_mfma_f32_32x32x16_bf16(a, b, c, 0, 0, 0)

// ---- DPP-based wave64 reductions (VALU pipe, not LDS) ----
template<int CTRL, int RMASK>
__device__ __forceinline__ float dpp_sum_step(float v) {
    int x = __builtin_amdgcn_update_dpp(0, __float_as_int(v), CTRL, RMASK, 0xf, true);
    return v + __int_as_float(x);
}
template<int CTRL, int RMASK>
__device__ __forceinline__ float dpp_max_step(float v) {
    int x = __builtin_amdgcn_update_dpp(__float_as_int(v), __float_as_int(v), CTRL, RMASK, 0xf, false);
    return fmaxf(v, __int_as_float(x));
}
__device__ __forceinline__ float wsum(float v) {
    v = dpp_sum_step<0x111, 0xf>(v);
    v = dpp_sum_step<0x112, 0xf>(v);
    v = dpp_sum_step<0x114, 0xf>(v);
    v = dpp_sum_step<0x118, 0xf>(v);
    v = dpp_sum_step<0x142, 0xa>(v);
    v = dpp_sum_step<0x143, 0xc>(v);
    return __int_as_float(__builtin_amdgcn_readlane(__float_as_int(v), 63));
}
__device__ __forceinline__ float wmax(float v) {
    v = dpp_max_step<0x111, 0xf>(v);
    v = dpp_max_step<0x112, 0xf>(v);
    v = dpp_max_step<0x114, 0xf>(v);
    v = dpp_max_step<0x118, 0xf>(v);
    v = dpp_max_step<0x142, 0xa>(v);
    v = dpp_max_step<0x143, 0xc>(v);
    return __int_as_float(__builtin_amdgcn_readlane(__float_as_int(v), 63));
}
__device__ __forceinline__ float gelu_erf(float x) {
    return 0.5f * x * (1.0f + erff(x * 0.70710678f));
}

// bf16 RNE conversion + error-compensated split: x ~= hi + lo
__device__ __forceinline__ unsigned short f2bf(float x) {
    unsigned u = __float_as_uint(x);
    unsigned r = (u + 0x7fff + ((u >> 16) & 1)) >> 16;
    return (unsigned short)r;
}
__device__ __forceinline__ float bf2f(unsigned short h) {
    return __uint_as_float(((unsigned)h) << 16);
}
__device__ __forceinline__ void split_bf(float x, unsigned short& h, unsigned short& l) {
    h = f2bf(x);
    l = f2bf(x - bf2f(h));
}

// HW packed f32->bf16 RNE (identical rounding to f2bf), 2 values per inst.
__device__ __forceinline__ unsigned cvt_pk_bf(float lo, float hi) {
    unsigned r;
    asm("v_cvt_pk_bf16_f32 %0, %1, %2" : "=v"(r) : "v"(lo), "v"(hi));
    return r;
}
// pack 8 floats -> hi bf16x8 + lo bf16x8 (error-compensated split), as u32x4
__device__ __forceinline__ void pack8(const float* v, u32x4& h, u32x4& l) {
#pragma unroll
    for (int j = 0; j < 4; ++j) {
        float a = v[2 * j], b = v[2 * j + 1];
        unsigned hp = cvt_pk_bf(a, b);
        float ra = a - __uint_as_float(hp << 16);
        float rb = b - __uint_as_float(hp & 0xffff0000u);
        h[j] = hp;
        l[j] = cvt_pk_bf(ra, rb);
    }
}
__device__ __forceinline__ bf16x8 as_bf(u32x4 x) {
    union { u32x4 u; bf16x8 b; } c; c.u = x; return c.b;
}
// load a bf16x8 fragment from LDS (8-byte aligned, padded-stride rows)
__device__ __forceinline__ bf16x8 ld8(const short* p) {
    s16x4 a = *(const s16x4*)p;
    s16x4 b = *(const s16x4*)(p + 4);
    bf16x8 r;
    r[0] = a[0]; r[1] = a[1]; r[2] = a[2]; r[3] = a[3];
    r[4] = b[0]; r[5] = b[1]; r[6] = b[2]; r[7] = b[3];
    return r;
}

// h[b,l,:] = x[b,l,:] @ rp_w + rp_b + pos[l,:]
__global__ void k_h_init(const float* __restrict__ x, const float* __restrict__ rp_w,
                         const float* __restrict__ rp_b, const float* __restrict__ pos,
                         float* __restrict__ h) {
    __shared__ float xs[48];
    int row = blockIdx.x;            // b*L + l
    int l = row % LSEQ;
    int t = threadIdx.x;
    if (t < 48) xs[t] = x[row * 48 + t];
    __syncthreads();
    float acc = rp_b[t] + pos[l * HD + t];
#pragma unroll 8
    for (int a = 0; a < 48; ++a) acc += xs[a] * rp_w[a * HD + t];
    h[row * HD + t] = acc;
}

// pA[row,:] = h[row,:] @ wA (+ bA);  pB[row,:] = h[row,:] @ wB (+ bB)
// center!=0: subtract per-row mean (LN-mean elimination downstream)
__global__ void k_proj2(const float* __restrict__ h, const float* __restrict__ wA,
                        const float* __restrict__ wB, const float* __restrict__ bA,
                        const float* __restrict__ bB, int center,
                        float* __restrict__ pA, float* __restrict__ pB) {
    __shared__ float hs[HD];
    int row = blockIdx.x;
    int t = threadIdx.x;
    hs[t] = h[row * HD + t];
    hs[t + 128] = h[row * HD + t + 128];
    __syncthreads();
    int col = t & 63;
    const float* w = (t < 64) ? wA : wB;
    const float* bias = (t < 64) ? bA : bB;
    float acc = bias ? bias[col] : 0.0f;
#pragma unroll 8
    for (int a = 0; a < HD; ++a) acc += hs[a] * w[a * PDIM + col];
    if (center) {
        float mean = wsum(acc) * (1.0f / PDIM);
        acc -= mean;
    }
    float* p = (t < 64) ? pA : pB;
    p[row * PDIM + col] = acc;
}

// pair[b,i,j,:] = pi[b,i,:] + pj[b,j,:] + rel_emb[clip(j-i)+32,:]
// 1-wave blocks of 32 j; fused layer-0 mask epilogue (LN(pair).pbs -> atomicAdd).
__global__ void __launch_bounds__(64) k_pair_init2(
    const float* __restrict__ pi, const float* __restrict__ pj,
    const float* __restrict__ rel_emb, const float* __restrict__ gpb,
    const float* __restrict__ cbv, float* __restrict__ pair,
    float* __restrict__ mask_out) {
    __shared__ __align__(16) float pt[32][65];
    int blk = blockIdx.x;            // row*12 + seg
    int row = blk / 12, seg = blk % 12;
    int b = row / LSEQ, i = row % LSEQ;
    int t = threadIdx.x;             // 0..63
    int pl = t & 31, hq = t >> 5;
    int j0 = seg * 32;
    float piv = pi[row * 64 + t];
    const float* pjb = pj + ((size_t)b * LSEQ + j0) * 64;
#pragma unroll 8
    for (int j = 0; j < 32; ++j) {
        int r = j0 + j - i; r = r < -32 ? -32 : (r > 32 ? 32 : r); r += 32;
        pt[j][t] = piv + pjb[j * 64 + t] + rel_emb[r * 64 + t];
    }
    __syncthreads();
    // stage-out to global, coalesced float4 (element-mapped past the pad)
    float4* dst4 = (float4*)(pair + ((size_t)row * LSEQ + j0) * 64);
    for (int n = t; n < 512; n += 64) {
        int r2 = n >> 4, c4 = (n & 15) << 2;
        float4 g4 = { pt[r2][c4], pt[r2][c4 + 1], pt[r2][c4 + 2], pt[r2][c4 + 3] };
        dst4[n] = g4;
    }
    // fused layer-0 mask: dot = rsqrt(var) * sum(d * g*pbs) + sum(b*pbs)
    float vv[32];
    float sv = 0.0f;
#pragma unroll
    for (int c = 0; c < 32; ++c) { vv[c] = pt[pl][hq * 32 + c]; sv += vv[c]; }
    sv += __shfl_xor(sv, 32);
    float mean = sv * (1.0f / PDIM);
    float sd2 = 0.0f, sdg = 0.0f;
#pragma unroll
    for (int c = 0; c < 32; ++c) {
        float d = vv[c] - mean;
        sd2 = fmaf(d, d, sd2);
        sdg = fmaf(d, gpb[hq * 32 + c], sdg);
    }
    sd2 += __shfl_xor(sd2, 32);
    sdg += __shfl_xor(sdg, 32);
    float rsv = rsqrtf(sd2 * (1.0f / PDIM) + 1e-5f);
    float dot = rsv * sdg + cbv[0];
    if (hq == 0)
        atomicAdd(mask_out + i * LSEQ + j0 + pl, dot * (1.0f / (BATCH * NHEAD)));
}

// prep: fold LN g/b into W1 (b1p = b1 + bb@W1), split all pair-MLP weights into
// bf16 hi/lo, stored TRANSPOSED [out][k] for direct 16B MFMA A-frag loads.
__global__ void k_prep(const float* __restrict__ pu_ln_g, const float* __restrict__ pu_ln_b,
                       const float* __restrict__ pu_w1, const float* __restrict__ pu_b1,
                       const float* __restrict__ pu_w2,
                       const float* __restrict__ dh_ln_g, const float* __restrict__ dh_ln_b,
                       const float* __restrict__ dh_w1, const float* __restrict__ dh_b1,
                       const float* __restrict__ dh_w2,
                       unsigned short* __restrict__ w1hT, unsigned short* __restrict__ w1lT,
                       unsigned short* __restrict__ w2hT, unsigned short* __restrict__ w2lT,
                       float* __restrict__ b1p, float* __restrict__ w2c) {
    int i = blockIdx.x;              // 0..4
    int c = threadIdx.x;             // 0..63 = output row of transposed arrays
    const float *g, *bb, *w1, *b1, *w2;
    int w2s;
    if (i < 4) { g = pu_ln_g + i * 64; bb = pu_ln_b + i * 64; w1 = pu_w1 + i * 4096;
                 b1 = pu_b1 + i * 64; w2 = pu_w2 + i * 4096; w2s = 64; }
    else       { g = dh_ln_g; bb = dh_ln_b; w1 = dh_w1; b1 = dh_b1; w2 = dh_w2; w2s = 65; }
    float accb = b1[c];
    for (int k = 0; k < 64; ++k) {
        float wv = w1[k * 64 + c];
        accb += bb[k] * wv;
        unsigned short h, l;
        split_bf(g[k] * wv, h, l);                 // W1'[k][c] stored at [c][k]
        w1hT[i * 4096 + c * 64 + k] = h;
        w1lT[i * 4096 + c * 64 + k] = l;
        split_bf(w2[k * w2s + c], h, l);           // W2[k][c] stored at [c][k]
        w2hT[i * 4096 + c * 64 + k] = h;
        w2lT[i * 4096 + c * 64 + k] = l;
    }
    b1p[i * 64 + c] = accb;
    if (i == 4) w2c[c] = dh_w2[c * 65 + 64];
}

// prep for fused mask: gp[li][c] = ln_pair_g[li][c] * pbs[c],
// cb[li] = sum_c ln_pair_b[li][c]*pbs[c], pbs[c] = sum_h pb_w[li][c][h]. li=0..3.
__global__ void k_maskprep(const float* __restrict__ g, const float* __restrict__ bb,
                           const float* __restrict__ pbw, float* __restrict__ gp,
                           float* __restrict__ cb) {
    int li = blockIdx.x;             // layer 0..3
    int c = threadIdx.x;             // 0..63 (one wave)
    const float* pw = pbw + li * PDIM * NHEAD;
    float pbs = pw[c * 4] + pw[c * 4 + 1] + pw[c * 4 + 2] + pw[c * 4 + 3];
    gp[li * 64 + c] = g[li * 64 + c] * pbs;
    float s = wsum(bb[li * 64 + c] * pbs);
    if (c == 0) cb[li] = s;
}

// prep: split+transpose seq weights to bf16 hi/lo [n][k] via 64x64 LDS tiles.
// src: [K][N] row-major, per-layer stride sstride; dst: [N][K], stride dstride.
__global__ void k_split_T(const float* __restrict__ src, unsigned short* __restrict__ dh,
                          unsigned short* __restrict__ dl, int K, int N,
                          int tiles_k, int tiles_n, size_t sstride, size_t dstride) {
    __shared__ float lds[64][65];
    int bid = blockIdx.x;
    int tpl = tiles_k * tiles_n;
    int layer = bid / tpl;
    int rest = bid % tpl;
    int kt = rest / tiles_n, nt = rest % tiles_n;
    const float* s = src + layer * sstride;
    int t = threadIdx.x, c = t & 63, r0 = t >> 6;
    for (int r = r0; r < 64; r += 4)
        lds[r][c] = s[(size_t)(kt * 64 + r) * N + nt * 64 + c];
    __syncthreads();
    unsigned short* oh = dh + layer * dstride;
    unsigned short* ol = dl + layer * dstride;
    for (int r = r0; r < 64; r += 4) {
        float v = lds[c][r];                       // src[kt*64+c][nt*64+r]
        unsigned short h, l;
        split_bf(v, h, l);
        size_t o = (size_t)(nt * 64 + r) * K + kt * 64 + c;
        oh[o] = h;
        ol[o] = l;
    }
}

// ============ generic MFMA seq GEMM ============
// OUT[m][n] = epi( X[m][:]@W + bias[n] + (R?R[m][n]:0) ), M=768 rows.
// W pre-split bf16 hi/lo transposed [n][k]. Wave = 32x32 tile, block = 4 waves.
template<bool GELU>
__global__ void __launch_bounds__(256) k_gemm(
    const float* __restrict__ X, const unsigned short* __restrict__ wTh,
    const unsigned short* __restrict__ wTl, const float* __restrict__ bias,
    const float* __restrict__ R, float* __restrict__ OUT, int K, int N) {
    int idx = blockIdx.x * 4 + (threadIdx.x >> 6);
    int lane = threadIdx.x & 63;
    int pl = lane & 31, hq = lane >> 5;
    int ntiles = N >> 5;
    int mt = idx / ntiles, nt = idx % ntiles;
    const float* xr = X + (size_t)(mt * 32 + pl) * K + 8 * hq;
    const unsigned short* bh = wTh + (size_t)(nt * 32 + pl) * K + 8 * hq;
    const unsigned short* bl = wTl + (size_t)(nt * 32 + pl) * K + 8 * hq;
    int n = nt * 32 + pl;
    float bv = bias[n];
    f32x16 acc;
#pragma unroll
    for (int r = 0; r < 16; ++r) {
        int mr = mt * 32 + (r & 3) + 8 * (r >> 2) + 4 * hq;
        acc[r] = bv + (R ? R[(size_t)mr * N + n] : 0.0f);
    }
#pragma unroll 4
    for (int s = 0; s < K; s += 16) {
        const f32x4* x4 = (const f32x4*)(xr + s);
        f32x4 xa = x4[0], xb = x4[1];
        float xv[8];
#pragma unroll
        for (int j = 0; j < 4; ++j) { xv[j] = xa[j]; xv[4 + j] = xb[j]; }
        u32x4 ah, al;
        pack8(xv, ah, al);
        bf16x8 bhv = *(const bf16x8*)(bh + s);
        bf16x8 blv = *(const bf16x8*)(bl + s);
        acc = MFMA32(as_bf(ah), bhv, acc);
        acc = MFMA32(as_bf(al), bhv, acc);
        acc = MFMA32(as_bf(ah), blv, acc);
    }
#pragma unroll
    for (int r = 0; r < 16; ++r) {
        int mr = mt * 32 + (r & 3) + 8 * (r >> 2) + 4 * hq;
        float v = acc[r];
        OUT[(size_t)mr * N + n] = GELU ? gelu_erf(v) : v;
    }
}

// seq layernorm: one row per block
__global__ void k_ln_seq(const float* __restrict__ h, const float* __restrict__ g,
                         const float* __restrict__ b, float* __restrict__ out) {
    __shared__ float red[8];
    int row = blockIdx.x;
    int t = threadIdx.x;
    int w = t >> 6, lane = t & 63;
    float v = h[row * HD + t];
    float s = wsum(v);
    if (lane == 0) red[w] = s;
    __syncthreads();
    float mean = (red[0] + red[1] + red[2] + red[3]) * (1.0f / HD);
    float d = v - mean;
    float q = wsum(d * d);
    if (lane == 0) red[4 + w] = q;
    __syncthreads();
    float var = (red[4] + red[5] + red[6] + red[7]) * (1.0f / HD);
    out[row * HD + t] = d * rsqrtf(var + 1e-5f) * g[t] + b[t];
}

// attention for one (b, nh, l) per block
__global__ void k_attn(const float* __restrict__ qkv, const float* __restrict__ mask,
                       float* __restrict__ o) {
    __shared__ __align__(16) float qs[64];
    __shared__ float sc[LSEQ];
    __shared__ float red[8];
    __shared__ float op[4][64];
    int bid = blockIdx.x;
    int l = bid % LSEQ;
    int nh = (bid / LSEQ) & 3;
    int b = bid / (LSEQ * NHEAD);
    int t = threadIdx.x;
    int w = t >> 6, lane = t & 63;
    const float* qbase = qkv + ((size_t)(b * LSEQ + l)) * 768 + nh * 64;
    if (t < 64) qs[t] = qbase[t];
    __syncthreads();
    float lmax = -1e30f;
    float myv[2];
#pragma unroll
    for (int it = 0; it < 2; ++it) {
        int m = t + it * 256;
        if (m < LSEQ) {
            const float* kb = qkv + ((size_t)(b * LSEQ + m)) * 768 + 256 + nh * 64;
            const float4* k4 = (const float4*)kb;
            const float4* q4 = (const float4*)qs;
            float acc = 0.0f;
#pragma unroll
            for (int a = 0; a < 16; ++a) {
                float4 kv = k4[a], qv = q4[a];
                acc += qv.x * kv.x + qv.y * kv.y + qv.z * kv.z + qv.w * kv.w;
            }
            float s = acc * 0.125f + mask[l * LSEQ + m];
            myv[it] = s;
            lmax = fmaxf(lmax, s);
        } else myv[it] = -1e30f;
    }
    float wm = wmax(lmax);
    if (lane == 0) red[w] = wm;
    __syncthreads();
    float gmax = fmaxf(fmaxf(red[0], red[1]), fmaxf(red[2], red[3]));
    float lsum = 0.0f;
#pragma unroll
    for (int it = 0; it < 2; ++it) {
        int m = t + it * 256;
        if (m < LSEQ) {
            float e = expf(myv[it] - gmax);
            sc[m] = e;
            lsum += e;
        }
    }
    float ws = wsum(lsum);
    if (lane == 0) red[4 + w] = ws;
    __syncthreads();
    float inv = 1.0f / (red[4] + red[5] + red[6] + red[7]);
    int d = t & 63, gq = t >> 6;
    float part = 0.0f;
    for (int m = gq * 96; m < (gq + 1) * 96; ++m)
        part += sc[m] * qkv[((size_t)(b * LSEQ + m)) * 768 + 512 + nh * 64 + d];
    op[gq][d] = part;
    __syncthreads();
    if (t < 64) {
        float ov = (op[0][t] + op[1][t] + op[2][t] + op[3][t]) * inv;
        o[((size_t)(b * LSEQ + l)) * HD + nh * 64 + t] = ov;
    }
}

// ============ MFMA pair-update v3: LDS-resident weights, 4-wave blocks ============
// Block = 256 threads = 4 waves, 128 j per block. All MLP weights staged once
// into LDS (padded stride 68 shorts -> 2-way bank on b64 reads = free); the
// per-wave MFMA chain reads fragments via lgkm (no vmcnt stalls). Pair residual
// read/modify/write is lane-private float4 x8 (channels form 4 contiguous runs).
// !DIST: fused next-layer mask. DIST: dist-head fused; pair never hits HBM.
template<bool DIST>
__global__ void __launch_bounds__(256) k_pair_upd(
    const float* __restrict__ ojc,   // centered oj         (B,L,64)
    const float* __restrict__ oic,   // centered oi+outer_b (B,L,64)
    const unsigned short* __restrict__ w1hT, const unsigned short* __restrict__ w1lT,
    const float* __restrict__ b1p,
    const unsigned short* __restrict__ w2hT, const unsigned short* __restrict__ w2lT,
    const float* __restrict__ b2, float* __restrict__ pair,
    const float* __restrict__ gpb, const float* __restrict__ cbv,
    float* __restrict__ mask_out,
    const unsigned short* __restrict__ dw1h, const unsigned short* __restrict__ dw1l,
    const float* __restrict__ db1p,
    const unsigned short* __restrict__ dw2h, const unsigned short* __restrict__ dw2l,
    const float* __restrict__ w2c, const float* __restrict__ db2,
    float* __restrict__ outg) {
    __shared__ short lw[4][64][68];              // w1h | w1l | w2h | w2l (padded)
    constexpr int PTR = DIST ? 128 : 1;
    __shared__ __align__(16) float pt[PTR][65];  // DIST only: reorder/output tile
    int blk = blockIdx.x;            // row*3 + seg
    int row = blk / 3, seg = blk % 3;
    int b = row / LSEQ;
    int t = threadIdx.x;
    int wave = t >> 6, lane = t & 63;
    int pl = lane & 31, hq = lane >> 5;
    int jj = wave * 32 + pl;         // 0..127 within segment
    int p = seg * 128 + jj;
    const float* ojr = ojc + ((size_t)b * LSEQ + p) * 64;
    const float* oir = oic + (size_t)row * 64;
    float* prp = pair + ((size_t)row * LSEQ + p) * 64;

    // ---- v = oj + oi, vectorized (global loads overlap the LDS staging) ----
    float v[32];
    {
        const f32x4* a4 = (const f32x4*)ojr;
        const f32x4* c4 = (const f32x4*)oir;
#pragma unroll
        for (int s = 0; s < 4; ++s) {
            f32x4 a = a4[4 * s + 2 * hq], aa = a4[4 * s + 2 * hq + 1];
            f32x4 c = c4[4 * s + 2 * hq], cc = c4[4 * s + 2 * hq + 1];
#pragma unroll
            for (int j = 0; j < 4; ++j) {
                v[8 * s + j] = a[j] + c[j];
                v[8 * s + 4 + j] = aa[j] + cc[j];
            }
        }
    }
    // ---- stage all 4 weight arrays into LDS (32KB, coop, coalesced) ----
#define STAGE_W(a2, src) \
    for (int idx = t; idx < 2048; idx += 256) { \
        int rr2 = idx >> 5, cc2 = idx & 31; \
        *(unsigned*)(&lw[a2][rr2][cc2 * 2]) = *(const unsigned*)(src + rr2 * 64 + cc2 * 2); \
    }
    STAGE_W(0, w1hT)
    STAGE_W(1, w1lT)
    STAGE_W(2, w2hT)
    STAGE_W(3, w2lT)

    // LN (mean already removed upstream) + bf16 hi/lo pack via cvt_pk
    float ss = 0.0f;
#pragma unroll
    for (int i = 0; i < 32; ++i) ss = fmaf(v[i], v[i], ss);
    ss += __shfl_xor(ss, 32);
    float rs = rsqrtf(ss * (1.0f / PDIM) + 1e-5f);
#pragma unroll
    for (int i = 0; i < 32; ++i) v[i] *= rs;
    u32x4 zh[4], zl[4];
#pragma unroll
    for (int s = 0; s < 4; ++s) pack8(v + 8 * s, zh[s], zl[s]);

    // bias vectors as float4 (channel pattern rr = (r&3)+8*(r>>2)+4hq)
    const f32x4* b14 = (const f32x4*)b1p;
    f32x4 bi0[4], bi1[4];
#pragma unroll
    for (int g = 0; g < 4; ++g) { bi0[g] = b14[2 * g + hq]; bi1[g] = b14[8 + 2 * g + hq]; }

    __syncthreads();   // weights staged

    f32x16 acc0, acc1;
#pragma unroll
    for (int r = 0; r < 16; ++r) {
        acc0[r] = bi0[r >> 2][r & 3];
        acc1[r] = bi1[r >> 2][r & 3];
    }
#pragma unroll
    for (int s = 0; s < 4; ++s) {
        int ko = 16 * s + 8 * hq;
        bf16x8 a0h = ld8(&lw[0][pl][ko]);
        bf16x8 a0l = ld8(&lw[1][pl][ko]);
        bf16x8 a1h = ld8(&lw[0][32 + pl][ko]);
        bf16x8 a1l = ld8(&lw[1][32 + pl][ko]);
        bf16x8 zhs = as_bf(zh[s]), zls = as_bf(zl[s]);
        acc0 = MFMA32(a0h, zhs, acc0);
        acc0 = MFMA32(a0h, zls, acc0);
        acc0 = MFMA32(a0l, zhs, acc0);
        acc1 = MFMA32(a1h, zhs, acc1);
        acc1 = MFMA32(a1h, zls, acc1);
        acc1 = MFMA32(a1l, zhs, acc1);
    }
    float u0[16], u1[16];
#pragma unroll
    for (int r = 0; r < 16; ++r) { u0[r] = gelu_erf(acc0[r]); u1[r] = gelu_erf(acc1[r]); }

    // residual + bias2 prefetch (latency hidden under shuffles/packing below)
    f32x4 r0[4], r1[4], q0[4], q1[4];
    {
        const f32x4* pr4 = (const f32x4*)prp;
        const f32x4* b24 = (const f32x4*)b2;
#pragma unroll
        for (int g = 0; g < 4; ++g) {
            r0[g] = pr4[2 * g + hq];
            r1[g] = pr4[8 + 2 * g + hq];
            q0[g] = b24[2 * g + hq];
            q1[g] = b24[8 + 2 * g + hq];
        }
    }

    float rA0[4], rB0[4], rA1[4], rB1[4];
#pragma unroll
    for (int i = 0; i < 4; ++i) {
        rA0[i] = __shfl_xor(hq ? u0[i] : u0[4 + i], 32);
        rB0[i] = __shfl_xor(hq ? u0[8 + i] : u0[12 + i], 32);
        rA1[i] = __shfl_xor(hq ? u1[i] : u1[4 + i], 32);
        rB1[i] = __shfl_xor(hq ? u1[8 + i] : u1[12 + i], 32);
    }
    u32x4 uh[4], ul[4];
#pragma unroll
    for (int s = 0; s < 4; ++s) {
        int tt = s >> 1, q = s & 1;
        float fg[8];
#pragma unroll
        for (int i = 0; i < 4; ++i) {
            float own_f = q ? (tt ? u1[8 + i] : u0[8 + i]) : (tt ? u1[i] : u0[i]);
            float own_s = q ? (tt ? u1[12 + i] : u0[12 + i]) : (tt ? u1[4 + i] : u0[4 + i]);
            float rcv   = q ? (tt ? rB1[i] : rB0[i]) : (tt ? rA1[i] : rA0[i]);
            fg[i]     = hq ? rcv : own_f;
            fg[4 + i] = hq ? own_s : rcv;
        }
        pack8(fg, uh[s], ul[s]);
    }

    f32x16 c0, c1;
#pragma unroll
    for (int r = 0; r < 16; ++r) {
        int g = r >> 2, i = r & 3;
        c0[r] = q0[g][i] + r0[g][i];
        c1[r] = q1[g][i] + r1[g][i];
    }
#pragma unroll
    for (int s = 0; s < 4; ++s) {
        int ko = 16 * s + 8 * hq;
        bf16x8 a0h = ld8(&lw[2][pl][ko]);
        bf16x8 a0l = ld8(&lw[3][pl][ko]);
        bf16x8 a1h = ld8(&lw[2][32 + pl][ko]);
        bf16x8 a1l = ld8(&lw[3][32 + pl][ko]);
        bf16x8 uhs = as_bf(uh[s]), uls = as_bf(ul[s]);
        c0 = MFMA32(a0h, uhs, c0);
        c0 = MFMA32(a0h, uls, c0);
        c0 = MFMA32(a0l, uhs, c0);
        c1 = MFMA32(a1h, uhs, c1);
        c1 = MFMA32(a1h, uls, c1);
        c1 = MFMA32(a1l, uhs, c1);
    }

    if constexpr (!DIST) {
        // fused mask for next layer: LN(final pair) . pbsum, mean over b via atomics
        const f32x4* gp4 = (const f32x4*)gpb;
        f32x4 gp0[4], gp1[4];
#pragma unroll
        for (int g = 0; g < 4; ++g) { gp0[g] = gp4[2 * g + hq]; gp1[g] = gp4[8 + 2 * g + hq]; }
        float sv = 0.0f;
#pragma unroll
        for (int r = 0; r < 16; ++r) sv += c0[r] + c1[r];
        sv += __shfl_xor(sv, 32);
        float mean = sv * (1.0f / PDIM);
        float sd2 = 0.0f, sdg = 0.0f;
#pragma unroll 4
        for (int r = 0; r < 16; ++r) {
            int g = r >> 2, i = r & 3;
            float d0 = c0[r] - mean, d1 = c1[r] - mean;
            sd2 = fmaf(d0, d0, sd2);
            sd2 = fmaf(d1, d1, sd2);
            sdg = fmaf(d0, gp0[g][i], sdg);
            sdg = fmaf(d1, gp1[g][i], sdg);
        }
        sd2 += __shfl_xor(sd2, 32);
        sdg += __shfl_xor(sdg, 32);
        float rsv = rsqrtf(sd2 * (1.0f / PDIM) + 1e-5f);
        float dot = rsv * sdg + cbv[0];
        if (hq == 0)
            atomicAdd(mask_out + (row % LSEQ) * LSEQ + p, dot * (1.0f / (BATCH * NHEAD)));
        // store updated pair: lane-private float4 x8
        f32x4* pw4 = (f32x4*)prp;
#pragma unroll
        for (int g = 0; g < 4; ++g) {
            f32x4 s0, s1;
#pragma unroll
            for (int i = 0; i < 4; ++i) { s0[i] = c0[4 * g + i]; s1[i] = c1[4 * g + i]; }
            pw4[2 * g + hq] = s0;
            pw4[8 + 2 * g + hq] = s1;
        }
    } else {
        // ---- fused distogram head: final pair only in regs/LDS ----
        // fragment layout -> k-order via private pt rows (same-wave, no barrier)
#pragma unroll
        for (int r = 0; r < 16; ++r) {
            int rr = (r & 3) + 8 * (r >> 2) + 4 * hq;
            pt[jj][rr] = c0[r];
            pt[jj][32 + rr] = c1[r];
        }
        float v2[32];
#pragma unroll
        for (int s = 0; s < 4; ++s) {
            int k0 = 16 * s + 8 * hq;
#pragma unroll
            for (int j = 0; j < 8; ++j) v2[8 * s + j] = pt[jj][k0 + j];
        }
        float sm = 0.0f;
#pragma unroll
        for (int i = 0; i < 32; ++i) sm += v2[i];
        sm += __shfl_xor(sm, 32);
        float mean = sm * (1.0f / PDIM);
        float ss2 = 0.0f;
#pragma unroll
        for (int i = 0; i < 32; ++i) { v2[i] -= mean; ss2 = fmaf(v2[i], v2[i], ss2); }
        ss2 += __shfl_xor(ss2, 32);
        float rs2 = rsqrtf(ss2 * (1.0f / PDIM) + 1e-5f);
#pragma unroll
        for (int i = 0; i < 32; ++i) v2[i] *= rs2;
#pragma unroll
        for (int s = 0; s < 4; ++s) pack8(v2 + 8 * s, zh[s], zl[s]);

        // re-stage LDS with dist-head weights (all waves done with pu weights)
        __syncthreads();
        STAGE_W(0, dw1h)
        STAGE_W(1, dw1l)
        STAGE_W(2, dw2h)
        STAGE_W(3, dw2l)
        const f32x4* d14 = (const f32x4*)db1p;
        const f32x4* d24 = (const f32x4*)db2;
        const f32x4* wc4 = (const f32x4*)w2c;
        f32x4 di0[4], di1[4], e0[4], e1[4], wc0[4], wc1[4];
#pragma unroll
        for (int g = 0; g < 4; ++g) {
            di0[g] = d14[2 * g + hq]; di1[g] = d14[8 + 2 * g + hq];
            e0[g] = d24[2 * g + hq];  e1[g] = d24[8 + 2 * g + hq];
            wc0[g] = wc4[2 * g + hq]; wc1[g] = wc4[8 + 2 * g + hq];
        }
        __syncthreads();

#pragma unroll
        for (int r = 0; r < 16; ++r) {
            acc0[r] = di0[r >> 2][r & 3];
            acc1[r] = di1[r >> 2][r & 3];
        }
#pragma unroll
        for (int s = 0; s < 4; ++s) {
            int ko = 16 * s + 8 * hq;
            bf16x8 a0h = ld8(&lw[0][pl][ko]);
            bf16x8 a0l = ld8(&lw[1][pl][ko]);
            bf16x8 a1h = ld8(&lw[0][32 + pl][ko]);
            bf16x8 a1l = ld8(&lw[1][32 + pl][ko]);
            bf16x8 zhs = as_bf(zh[s]), zls = as_bf(zl[s]);
            acc0 = MFMA32(a0h, zhs, acc0);
            acc0 = MFMA32(a0h, zls, acc0);
            acc0 = MFMA32(a0l, zhs, acc0);
            acc1 = MFMA32(a1h, zhs, acc1);
            acc1 = MFMA32(a1h, zls, acc1);
            acc1 = MFMA32(a1l, zhs, acc1);
        }
        float p64 = 0.0f;
#pragma unroll
        for (int r = 0; r < 16; ++r) {
            int g = r >> 2, i = r & 3;
            u0[r] = gelu_erf(acc0[r]);
            u1[r] = gelu_erf(acc1[r]);
            p64 = fmaf(u0[r], wc0[g][i], p64);
            p64 = fmaf(u1[r], wc1[g][i], p64);
        }
        p64 += __shfl_xor(p64, 32);
#pragma unroll
        for (int i = 0; i < 4; ++i) {
            rA0[i] = __shfl_xor(hq ? u0[i] : u0[4 + i], 32);
            rB0[i] = __shfl_xor(hq ? u0[8 + i] : u0[12 + i], 32);
            rA1[i] = __shfl_xor(hq ? u1[i] : u1[4 + i], 32);
            rB1[i] = __shfl_xor(hq ? u1[8 + i] : u1[12 + i], 32);
        }
#pragma unroll
        for (int s = 0; s < 4; ++s) {
            int tt = s >> 1, q = s & 1;
            float fg[8];
#pragma unroll
            for (int i = 0; i < 4; ++i) {
                float own_f = q ? (tt ? u1[8 + i] : u0[8 + i]) : (tt ? u1[i] : u0[i]);
                float own_s = q ? (tt ? u1[12 + i] : u0[12 + i]) : (tt ? u1[4 + i] : u0[4 + i]);
                float rcv   = q ? (tt ? rB1[i] : rB0[i]) : (tt ? rA1[i] : rA0[i]);
                fg[i]     = hq ? rcv : own_f;
                fg[4 + i] = hq ? own_s : rcv;
            }
            pack8(fg, uh[s], ul[s]);
        }
#pragma unroll
        for (int r = 0; r < 16; ++r) {
            c0[r] = e0[r >> 2][r & 3];
            c1[r] = e1[r >> 2][r & 3];
        }
#pragma unroll
        for (int s = 0; s < 4; ++s) {
            int ko = 16 * s + 8 * hq;
            bf16x8 a0h = ld8(&lw[2][pl][ko]);
            bf16x8 a0l = ld8(&lw[3][pl][ko]);
            bf16x8 a1h = ld8(&lw[2][32 + pl][ko]);
            bf16x8 a1l = ld8(&lw[3][32 + pl][ko]);
            bf16x8 uhs = as_bf(uh[s]), uls = as_bf(ul[s]);
            c0 = MFMA32(a0h, uhs, c0);
            c0 = MFMA32(a0h, uls, c0);
            c0 = MFMA32(a0l, uhs, c0);
            c1 = MFMA32(a1h, uhs, c1);
            c1 = MFMA32(a1h, uls, c1);
            c1 = MFMA32(a1l, uhs, c1);
        }
        // stage logits into pt (own rows), then coalesced block copy-out
#pragma unroll
        for (int r = 0; r < 16; ++r) {
            int rr = (r & 3) + 8 * (r >> 2) + 4 * hq;
            pt[jj][rr] = c0[r];
            pt[jj][32 + rr] = c1[r];
        }
        if (hq == 0) pt[jj][64] = p64 + db2[64];
        __syncthreads();
        float4* dst = (float4*)(outg + ((size_t)row * LSEQ + seg * 128) * NBINS);
        const float4* srcl = (const float4*)&pt[0][0];
        for (int n = t; n < 128 * NBINS / 4; n += 256) dst[n] = srcl[n];
    }
#undef STAGE_W
}

// out = (out + out^T(1,2)) / 2, in place.  One 16x16 (l,m) tile pair per block
// (upper triangle incl diagonal); lanes run along the contiguous 65-bin axis.
__global__ void k_sym(float* __restrict__ out) {
    int u = blockIdx.x;
    int b = 0;
    if (u >= NTRI) { b = 1; u -= NTRI; }
    int lt = 0, rem = NTT;
    while (u >= rem) { u -= rem; ++lt; --rem; }
    int mt = lt + u;
    int t = threadIdx.x;
    int g = t >> 6, lane = t & 63;
    float* ob = out + (size_t)b * LSEQ * LSEQ * NBINS;
    for (int e = g; e < 256; e += 4) {
        int i = e >> 4, j = e & 15;
        if (lt == mt && j < i) continue;
        size_t ia = ((size_t)(lt * 16 + i) * LSEQ + (mt * 16 + j)) * NBINS;
        size_t ib = ((size_t)(mt * 16 + j) * LSEQ + (lt * 16 + i)) * NBINS;
        for (int k = lane; k < NBINS; k += 64) {
            float a = ob[ia + k], c = ob[ib + k];
            float vv = 0.5f * (a + c);
            ob[ia + k] = vv;
            if (ia != ib) ob[ib + k] = vv;
        }
    }
}

extern "C" void kernel_launch(void* const* d_in, const int* in_sizes, int n_in,
                              void* d_out, int out_size, void* d_ws, size_t ws_size,
                              hipStream_t stream) {
    const float* x        = (const float*)d_in[0];
    const float* rp_w     = (const float*)d_in[1];
    const float* rp_b     = (const float*)d_in[2];
    const float* pos      = (const float*)d_in[3];
    const float* pii_w    = (const float*)d_in[4];
    const float* pii_b    = (const float*)d_in[5];
    const float* pij_w    = (const float*)d_in[6];
    const float* pij_b    = (const float*)d_in[7];
    const float* rel_emb  = (const float*)d_in[8];
    const float* ln_seq_g = (const float*)d_in[9];
    const float* ln_seq_b = (const float*)d_in[10];
    const float* ln_pair_g= (const float*)d_in[11];
    const float* ln_pair_b= (const float*)d_in[12];
    const float* pb_w     = (const float*)d_in[13];
    const float* in_w     = (const float*)d_in[14];
    const float* in_b     = (const float*)d_in[15];
    const float* out_w    = (const float*)d_in[16];
    const float* out_b    = (const float*)d_in[17];
    const float* ff_ln_g  = (const float*)d_in[18];
    const float* ff_ln_b  = (const float*)d_in[19];
    const float* ff_w1    = (const float*)d_in[20];
    const float* ff_b1    = (const float*)d_in[21];
    const float* ff_w2    = (const float*)d_in[22];
    const float* ff_b2    = (const float*)d_in[23];
    const float* pu_ln_g  = (const float*)d_in[24];
    const float* pu_ln_b  = (const float*)d_in[25];
    const float* pu_w1    = (const float*)d_in[26];
    const float* pu_b1    = (const float*)d_in[27];
    const float* pu_w2    = (const float*)d_in[28];
    const float* pu_b2    = (const float*)d_in[29];
    const float* outer_w  = (const float*)d_in[30];
    const float* outer_b  = (const float*)d_in[31];
    const float* dh_ln_g  = (const float*)d_in[32];
    const float* dh_ln_b  = (const float*)d_in[33];
    const float* dh_w1    = (const float*)d_in[34];
    const float* dh_b1    = (const float*)d_in[35];
    const float* dh_w2    = (const float*)d_in[36];
    const float* dh_b2    = (const float*)d_in[37];
    float* outp = (float*)d_out;

    float* W = (float*)d_ws;
    float* h    = W;  W += BATCH * LSEQ * HD;
    float* sn   = W;  W += BATCH * LSEQ * HD;
    float* qkv  = W;  W += BATCH * LSEQ * 3 * HD;
    float* ob   = W;  W += BATCH * LSEQ * HD;
    float* mid  = W;  W += BATCH * LSEQ * 4 * HD;
    float* maskA= W;  W += LSEQ * LSEQ;
    float* maskB= W;  W += LSEQ * LSEQ;
    float* poi  = W;  W += BATCH * LSEQ * PDIM;
    float* poj  = W;  W += BATCH * LSEQ * PDIM;
    float* b1p  = W;  W += 5 * 64;
    float* w2c  = W;  W += 64;
    float* gpb  = W;  W += 4 * 64;
    float* cbv  = W;  W += 64;
    unsigned short* w1hT = (unsigned short*)W;  W += 5 * 2048;
    unsigned short* w1lT = (unsigned short*)W;  W += 5 * 2048;
    unsigned short* w2hT = (unsigned short*)W;  W += 5 * 2048;
    unsigned short* w2lT = (unsigned short*)W;  W += 5 * 2048;
    // seq-GEMM split/transposed weights (bf16 hi/lo), per-layer strides in elems
    unsigned short* qwT_h = (unsigned short*)W;  W += 4 * 196608 / 2;
    unsigned short* qwT_l = (unsigned short*)W;  W += 4 * 196608 / 2;
    unsigned short* owT_h = (unsigned short*)W;  W += 4 * 65536 / 2;
    unsigned short* owT_l = (unsigned short*)W;  W += 4 * 65536 / 2;
    unsigned short* f1T_h = (unsigned short*)W;  W += 4 * 262144 / 2;
    unsigned short* f1T_l = (unsigned short*)W;  W += 4 * 262144 / 2;
    unsigned short* f2T_h = (unsigned short*)W;  W += 4 * 262144 / 2;
    unsigned short* f2T_l = (unsigned short*)W;  W += 4 * 262144 / 2;
    float* pair = W;  W += (size_t)BATCH * LSEQ * LSEQ * PDIM;

    const int rows = BATCH * LSEQ;   // 768

    k_prep<<<5, 64, 0, stream>>>(pu_ln_g, pu_ln_b, pu_w1, pu_b1, pu_w2,
                                 dh_ln_g, dh_ln_b, dh_w1, dh_b1, dh_w2,
                                 w1hT, w1lT, w2hT, w2lT, b1p, w2c);
    k_maskprep<<<4, 64, 0, stream>>>(ln_pair_g, ln_pair_b, pb_w, gpb, cbv);
    k_split_T<<<4 * 4 * 12, 256, 0, stream>>>(in_w,  qwT_h, qwT_l, 256, 768,  4, 12, 196608, 196608);
    k_split_T<<<4 * 4 * 4,  256, 0, stream>>>(out_w, owT_h, owT_l, 256, 256,  4, 4,  65536,  65536);
    k_split_T<<<4 * 4 * 16, 256, 0, stream>>>(ff_w1, f1T_h, f1T_l, 256, 1024, 4, 16, 262144, 262144);
    k_split_T<<<4 * 16 * 4, 256, 0, stream>>>(ff_w2, f2T_h, f2T_l, 1024, 256, 16, 4, 262144, 262144);
    k_h_init<<<rows, 256, 0, stream>>>(x, rp_w, rp_b, pos, h);
    k_proj2<<<rows, 128, 0, stream>>>(h, pii_w, pij_w, pii_b, pij_b, 0, poi, poj);
    hipMemsetAsync(maskA, 0, LSEQ * LSEQ * sizeof(float), stream);
    // pair init with fused layer-0 mask
    k_pair_init2<<<rows * 12, 64, 0, stream>>>(poi, poj, rel_emb, gpb, cbv, pair, maskA);

    float* mcur = maskA;
    float* mnext = maskB;
    for (int i = 0; i < 4; ++i) {
        k_ln_seq<<<rows, 256, 0, stream>>>(h, ln_seq_g + i * HD, ln_seq_b + i * HD, sn);
        // qkv = sn @ in_w + in_b
        k_gemm<false><<<144, 256, 0, stream>>>(sn, qwT_h + i * 196608, qwT_l + i * 196608,
                                               in_b + i * 768, nullptr, qkv, 256, 768);
        k_attn<<<BATCH * NHEAD * LSEQ, 256, 0, stream>>>(qkv, mcur, ob);
        // h += ob @ out_w + out_b
        k_gemm<false><<<48, 256, 0, stream>>>(ob, owT_h + i * 65536, owT_l + i * 65536,
                                              out_b + i * 256, h, h, 256, 256);
        k_ln_seq<<<rows, 256, 0, stream>>>(h, ff_ln_g + i * HD, ff_ln_b + i * HD, sn);
        // mid = gelu(sn @ ff_w1 + b1)
        k_gemm<true><<<192, 256, 0, stream>>>(sn, f1T_h + i * 262144, f1T_l + i * 262144,
                                              ff_b1 + i * 1024, nullptr, mid, 256, 1024);
        // h += mid @ ff_w2 + b2
        k_gemm<false><<<48, 256, 0, stream>>>(mid, f2T_h + i * 262144, f2T_l + i * 262144,
                                              ff_b2 + i * 256, h, h, 1024, 256);
        // centered oi+outer_b (poi) and centered oj (poj)
        k_proj2<<<rows, 128, 0, stream>>>(h, outer_w + i * 2 * HD * PDIM,
                                          outer_w + i * 2 * HD * PDIM + HD * PDIM,
                                          outer_b + i * PDIM, nullptr, 1, poi, poj);
        if (i < 3) {
            hipMemsetAsync(mnext, 0, LSEQ * LSEQ * sizeof(float), stream);
            k_pair_upd<false><<<rows * 3, 256, 0, stream>>>(
                poj, poi,
                w1hT + i * 4096, w1lT + i * 4096, b1p + i * 64,
                w2hT + i * 4096, w2lT + i * 4096, pu_b2 + i * PDIM, pair,
                gpb + (i + 1) * 64, cbv + (i + 1), mnext,
                nullptr, nullptr, nullptr, nullptr, nullptr, nullptr, nullptr, nullptr);
            float* tmp = mcur; mcur = mnext; mnext = tmp;
        } else {
            // last layer: pair update fused with distogram head; pair never stored
            k_pair_upd<true><<<rows * 3, 256, 0, stream>>>(
                poj, poi,
                w1hT + 3 * 4096, w1lT + 3 * 4096, b1p + 3 * 64,
                w2hT + 3 * 4096, w2lT + 3 * 4096, pu_b2 + 3 * PDIM, pair,
                nullptr, nullptr, nullptr,
                w1hT + 4 * 4096, w1lT + 4 * 4096, b1p + 4 * 64,
                w2hT + 4 * 4096, w2lT + 4 * 4096, w2c, dh_b2, outp);
        }
    }

    k_sym<<<2 * NTRI, 256, 0, stream>>>(outp);
}

// Round 4
// 1050.288 us; speedup vs baseline: 1.2228x; 1.0632x over previous
//
#include <hip/hip_runtime.h>
#include <math.h>

#define LSEQ 384
#define HD 256
#define PDIM 64
#define NHEAD 4
#define NBINS 65
#define BATCH 2
#define NTT (LSEQ / 16)
#define NTRI (NTT * (NTT + 1) / 2)

typedef __attribute__((ext_vector_type(8))) short bf16x8;
typedef __attribute__((ext_vector_type(16))) float f32x16;
typedef __attribute__((ext_vector_type(4))) float f32x4;
typedef __attribute__((ext_vector_type(4))) unsigned u32x4;
typedef __attribute__((ext_vector_type(4))) short s16x4;
#define MFMA32(a, b, c) __builtin_amdgcn_mfma_f32_32x32x16_bf16(a, b, c, 0, 0, 0)

// ---- DPP-based wave64 reductions (VALU pipe, not LDS) ----
template<int CTRL, int RMASK>
__device__ __forceinline__ float dpp_sum_step(float v) {
    int x = __builtin_amdgcn_update_dpp(0, __float_as_int(v), CTRL, RMASK, 0xf, true);
    return v + __int_as_float(x);
}
template<int CTRL, int RMASK>
__device__ __forceinline__ float dpp_max_step(float v) {
    int x = __builtin_amdgcn_update_dpp(__float_as_int(v), __float_as_int(v), CTRL, RMASK, 0xf, false);
    return fmaxf(v, __int_as_float(x));
}
__device__ __forceinline__ float wsum(float v) {
    v = dpp_sum_step<0x111, 0xf>(v);
    v = dpp_sum_step<0x112, 0xf>(v);
    v = dpp_sum_step<0x114, 0xf>(v);
    v = dpp_sum_step<0x118, 0xf>(v);
    v = dpp_sum_step<0x142, 0xa>(v);
    v = dpp_sum_step<0x143, 0xc>(v);
    return __int_as_float(__builtin_amdgcn_readlane(__float_as_int(v), 63));
}
__device__ __forceinline__ float wmax(float v) {
    v = dpp_max_step<0x111, 0xf>(v);
    v = dpp_max_step<0x112, 0xf>(v);
    v = dpp_max_step<0x114, 0xf>(v);
    v = dpp_max_step<0x118, 0xf>(v);
    v = dpp_max_step<0x142, 0xa>(v);
    v = dpp_max_step<0x143, 0xc>(v);
    return __int_as_float(__builtin_amdgcn_readlane(__float_as_int(v), 63));
}
__device__ __forceinline__ float gelu_erf(float x) {
    return 0.5f * x * (1.0f + erff(x * 0.70710678f));
}

// bf16 RNE conversion + error-compensated split: x ~= hi + lo
__device__ __forceinline__ unsigned short f2bf(float x) {
    unsigned u = __float_as_uint(x);
    unsigned r = (u + 0x7fff + ((u >> 16) & 1)) >> 16;
    return (unsigned short)r;
}
__device__ __forceinline__ float bf2f(unsigned short h) {
    return __uint_as_float(((unsigned)h) << 16);
}
__device__ __forceinline__ void split_bf(float x, unsigned short& h, unsigned short& l) {
    h = f2bf(x);
    l = f2bf(x - bf2f(h));
}

// HW packed f32->bf16 RNE (identical rounding to f2bf), 2 values per inst.
__device__ __forceinline__ unsigned cvt_pk_bf(float lo, float hi) {
    unsigned r;
    asm("v_cvt_pk_bf16_f32 %0, %1, %2" : "=v"(r) : "v"(lo), "v"(hi));
    return r;
}
// pack 8 floats -> hi bf16x8 + lo bf16x8 (error-compensated split), as u32x4
__device__ __forceinline__ void pack8(const float* v, u32x4& h, u32x4& l) {
#pragma unroll
    for (int j = 0; j < 4; ++j) {
        float a = v[2 * j], b = v[2 * j + 1];
        unsigned hp = cvt_pk_bf(a, b);
        float ra = a - __uint_as_float(hp << 16);
        float rb = b - __uint_as_float(hp & 0xffff0000u);
        h[j] = hp;
        l[j] = cvt_pk_bf(ra, rb);
    }
}
__device__ __forceinline__ bf16x8 as_bf(u32x4 x) {
    union { u32x4 u; bf16x8 b; } c; c.u = x; return c.b;
}
// load a bf16x8 fragment from LDS (8-byte aligned, padded-stride rows)
__device__ __forceinline__ bf16x8 ld8(const short* p) {
    s16x4 a = *(const s16x4*)p;
    s16x4 b = *(const s16x4*)(p + 4);
    bf16x8 r;
    r[0] = a[0]; r[1] = a[1]; r[2] = a[2]; r[3] = a[3];
    r[4] = b[0]; r[5] = b[1]; r[6] = b[2]; r[7] = b[3];
    return r;
}

// h[b,l,:] = x[b,l,:] @ rp_w + rp_b + pos[l,:]
__global__ void k_h_init(const float* __restrict__ x, const float* __restrict__ rp_w,
                         const float* __restrict__ rp_b, const float* __restrict__ pos,
                         float* __restrict__ h) {
    __shared__ float xs[48];
    int row = blockIdx.x;            // b*L + l
    int l = row % LSEQ;
    int t = threadIdx.x;
    if (t < 48) xs[t] = x[row * 48 + t];
    __syncthreads();
    float acc = rp_b[t] + pos[l * HD + t];
#pragma unroll 8
    for (int a = 0; a < 48; ++a) acc += xs[a] * rp_w[a * HD + t];
    h[row * HD + t] = acc;
}

// pA[row,:] = h[row,:] @ wA (+ bA);  pB[row,:] = h[row,:] @ wB (+ bB)
// center!=0: subtract per-row mean (LN-mean elimination downstream)
__global__ void k_proj2(const float* __restrict__ h, const float* __restrict__ wA,
                        const float* __restrict__ wB, const float* __restrict__ bA,
                        const float* __restrict__ bB, int center,
                        float* __restrict__ pA, float* __restrict__ pB) {
    __shared__ float hs[HD];
    int row = blockIdx.x;
    int t = threadIdx.x;
    hs[t] = h[row * HD + t];
    hs[t + 128] = h[row * HD + t + 128];
    __syncthreads();
    int col = t & 63;
    const float* w = (t < 64) ? wA : wB;
    const float* bias = (t < 64) ? bA : bB;
    float acc = bias ? bias[col] : 0.0f;
#pragma unroll 8
    for (int a = 0; a < HD; ++a) acc += hs[a] * w[a * PDIM + col];
    if (center) {
        float mean = wsum(acc) * (1.0f / PDIM);
        acc -= mean;
    }
    float* p = (t < 64) ? pA : pB;
    p[row * PDIM + col] = acc;
}

// pair[b,i,j,:] = pi[b,i,:] + pj[b,j,:] + rel_emb[clip(j-i)+32,:]
// 1-wave blocks of 32 j; fused layer-0 mask epilogue (LN(pair).pbs -> atomicAdd).
__global__ void __launch_bounds__(64) k_pair_init2(
    const float* __restrict__ pi, const float* __restrict__ pj,
    const float* __restrict__ rel_emb, const float* __restrict__ gpb,
    const float* __restrict__ cbv, float* __restrict__ pair,
    float* __restrict__ mask_out) {
    __shared__ __align__(16) float pt[32][65];
    int blk = blockIdx.x;            // row*12 + seg
    int row = blk / 12, seg = blk % 12;
    int b = row / LSEQ, i = row % LSEQ;
    int t = threadIdx.x;             // 0..63
    int pl = t & 31, hq = t >> 5;
    int j0 = seg * 32;
    float piv = pi[row * 64 + t];
    const float* pjb = pj + ((size_t)b * LSEQ + j0) * 64;
#pragma unroll 8
    for (int j = 0; j < 32; ++j) {
        int r = j0 + j - i; r = r < -32 ? -32 : (r > 32 ? 32 : r); r += 32;
        pt[j][t] = piv + pjb[j * 64 + t] + rel_emb[r * 64 + t];
    }
    __syncthreads();
    // stage-out to global, coalesced float4 (element-mapped past the pad)
    float4* dst4 = (float4*)(pair + ((size_t)row * LSEQ + j0) * 64);
    for (int n = t; n < 512; n += 64) {
        int r2 = n >> 4, c4 = (n & 15) << 2;
        float4 g4 = { pt[r2][c4], pt[r2][c4 + 1], pt[r2][c4 + 2], pt[r2][c4 + 3] };
        dst4[n] = g4;
    }
    // fused layer-0 mask: dot = rsqrt(var) * sum(d * g*pbs) + sum(b*pbs)
    float vv[32];
    float sv = 0.0f;
#pragma unroll
    for (int c = 0; c < 32; ++c) { vv[c] = pt[pl][hq * 32 + c]; sv += vv[c]; }
    sv += __shfl_xor(sv, 32);
    float mean = sv * (1.0f / PDIM);
    float sd2 = 0.0f, sdg = 0.0f;
#pragma unroll
    for (int c = 0; c < 32; ++c) {
        float d = vv[c] - mean;
        sd2 = fmaf(d, d, sd2);
        sdg = fmaf(d, gpb[hq * 32 + c], sdg);
    }
    sd2 += __shfl_xor(sd2, 32);
    sdg += __shfl_xor(sdg, 32);
    float rsv = rsqrtf(sd2 * (1.0f / PDIM) + 1e-5f);
    float dot = rsv * sdg + cbv[0];
    if (hq == 0)
        atomicAdd(mask_out + i * LSEQ + j0 + pl, dot * (1.0f / (BATCH * NHEAD)));
}

// prep: fold LN g/b into W1 (b1p = b1 + bb@W1), split all pair-MLP weights into
// bf16 hi/lo, stored TRANSPOSED [out][k] for direct 16B MFMA A-frag loads.
__global__ void k_prep(const float* __restrict__ pu_ln_g, const float* __restrict__ pu_ln_b,
                       const float* __restrict__ pu_w1, const float* __restrict__ pu_b1,
                       const float* __restrict__ pu_w2,
                       const float* __restrict__ dh_ln_g, const float* __restrict__ dh_ln_b,
                       const float* __restrict__ dh_w1, const float* __restrict__ dh_b1,
                       const float* __restrict__ dh_w2,
                       unsigned short* __restrict__ w1hT, unsigned short* __restrict__ w1lT,
                       unsigned short* __restrict__ w2hT, unsigned short* __restrict__ w2lT,
                       float* __restrict__ b1p, float* __restrict__ w2c) {
    int i = blockIdx.x;              // 0..4
    int c = threadIdx.x;             // 0..63 = output row of transposed arrays
    const float *g, *bb, *w1, *b1, *w2;
    int w2s;
    if (i < 4) { g = pu_ln_g + i * 64; bb = pu_ln_b + i * 64; w1 = pu_w1 + i * 4096;
                 b1 = pu_b1 + i * 64; w2 = pu_w2 + i * 4096; w2s = 64; }
    else       { g = dh_ln_g; bb = dh_ln_b; w1 = dh_w1; b1 = dh_b1; w2 = dh_w2; w2s = 65; }
    float accb = b1[c];
    for (int k = 0; k < 64; ++k) {
        float wv = w1[k * 64 + c];
        accb += bb[k] * wv;
        unsigned short h, l;
        split_bf(g[k] * wv, h, l);                 // W1'[k][c] stored at [c][k]
        w1hT[i * 4096 + c * 64 + k] = h;
        w1lT[i * 4096 + c * 64 + k] = l;
        split_bf(w2[k * w2s + c], h, l);           // W2[k][c] stored at [c][k]
        w2hT[i * 4096 + c * 64 + k] = h;
        w2lT[i * 4096 + c * 64 + k] = l;
    }
    b1p[i * 64 + c] = accb;
    if (i == 4) w2c[c] = dh_w2[c * 65 + 64];
}

// prep for fused mask: gp[li][c] = ln_pair_g[li][c] * pbs[c],
// cb[li] = sum_c ln_pair_b[li][c]*pbs[c], pbs[c] = sum_h pb_w[li][c][h]. li=0..3.
__global__ void k_maskprep(const float* __restrict__ g, const float* __restrict__ bb,
                           const float* __restrict__ pbw, float* __restrict__ gp,
                           float* __restrict__ cb) {
    int li = blockIdx.x;             // layer 0..3
    int c = threadIdx.x;             // 0..63 (one wave)
    const float* pw = pbw + li * PDIM * NHEAD;
    float pbs = pw[c * 4] + pw[c * 4 + 1] + pw[c * 4 + 2] + pw[c * 4 + 3];
    gp[li * 64 + c] = g[li * 64 + c] * pbs;
    float s = wsum(bb[li * 64 + c] * pbs);
    if (c == 0) cb[li] = s;
}

// prep: split+transpose seq weights to bf16 hi/lo [n][k] via 64x64 LDS tiles.
// src: [K][N] row-major, per-layer stride sstride; dst: [N][K], stride dstride.
__global__ void k_split_T(const float* __restrict__ src, unsigned short* __restrict__ dh,
                          unsigned short* __restrict__ dl, int K, int N,
                          int tiles_k, int tiles_n, size_t sstride, size_t dstride) {
    __shared__ float lds[64][65];
    int bid = blockIdx.x;
    int tpl = tiles_k * tiles_n;
    int layer = bid / tpl;
    int rest = bid % tpl;
    int kt = rest / tiles_n, nt = rest % tiles_n;
    const float* s = src + layer * sstride;
    int t = threadIdx.x, c = t & 63, r0 = t >> 6;
    for (int r = r0; r < 64; r += 4)
        lds[r][c] = s[(size_t)(kt * 64 + r) * N + nt * 64 + c];
    __syncthreads();
    unsigned short* oh = dh + layer * dstride;
    unsigned short* ol = dl + layer * dstride;
    for (int r = r0; r < 64; r += 4) {
        float v = lds[c][r];                       // src[kt*64+c][nt*64+r]
        unsigned short h, l;
        split_bf(v, h, l);
        size_t o = (size_t)(nt * 64 + r) * K + kt * 64 + c;
        oh[o] = h;
        ol[o] = l;
    }
}

// ============ generic MFMA seq GEMM ============
// OUT[m][n] = epi( X[m][:]@W + bias[n] + (R?R[m][n]:0) ), M=768 rows.
// W pre-split bf16 hi/lo transposed [n][k]. ONE 32x32 wave-tile per 64-thread
// block; grid = #tiles (spreads small GEMMs across all 256 CUs).
template<bool GELU>
__global__ void __launch_bounds__(64) k_gemm(
    const float* __restrict__ X, const unsigned short* __restrict__ wTh,
    const unsigned short* __restrict__ wTl, const float* __restrict__ bias,
    const float* __restrict__ R, float* __restrict__ OUT, int K, int N) {
    int idx = blockIdx.x;
    int lane = threadIdx.x & 63;
    int pl = lane & 31, hq = lane >> 5;
    int ntiles = N >> 5;
    int mt = idx / ntiles, nt = idx % ntiles;
    const float* xr = X + (size_t)(mt * 32 + pl) * K + 8 * hq;
    const unsigned short* bh = wTh + (size_t)(nt * 32 + pl) * K + 8 * hq;
    const unsigned short* bl = wTl + (size_t)(nt * 32 + pl) * K + 8 * hq;
    int n = nt * 32 + pl;
    float bv = bias[n];
    f32x16 acc;
#pragma unroll
    for (int r = 0; r < 16; ++r) {
        int mr = mt * 32 + (r & 3) + 8 * (r >> 2) + 4 * hq;
        acc[r] = bv + (R ? R[(size_t)mr * N + n] : 0.0f);
    }
#pragma unroll 4
    for (int s = 0; s < K; s += 16) {
        const f32x4* x4 = (const f32x4*)(xr + s);
        f32x4 xa = x4[0], xb = x4[1];
        float xv[8];
#pragma unroll
        for (int j = 0; j < 4; ++j) { xv[j] = xa[j]; xv[4 + j] = xb[j]; }
        u32x4 ah, al;
        pack8(xv, ah, al);
        bf16x8 bhv = *(const bf16x8*)(bh + s);
        bf16x8 blv = *(const bf16x8*)(bl + s);
        acc = MFMA32(as_bf(ah), bhv, acc);
        acc = MFMA32(as_bf(al), bhv, acc);
        acc = MFMA32(as_bf(ah), blv, acc);
    }
#pragma unroll
    for (int r = 0; r < 16; ++r) {
        int mr = mt * 32 + (r & 3) + 8 * (r >> 2) + 4 * hq;
        float v = acc[r];
        OUT[(size_t)mr * N + n] = GELU ? gelu_erf(v) : v;
    }
}

// seq layernorm: one row per block
__global__ void k_ln_seq(const float* __restrict__ h, const float* __restrict__ g,
                         const float* __restrict__ b, float* __restrict__ out) {
    __shared__ float red[8];
    int row = blockIdx.x;
    int t = threadIdx.x;
    int w = t >> 6, lane = t & 63;
    float v = h[row * HD + t];
    float s = wsum(v);
    if (lane == 0) red[w] = s;
    __syncthreads();
    float mean = (red[0] + red[1] + red[2] + red[3]) * (1.0f / HD);
    float d = v - mean;
    float q = wsum(d * d);
    if (lane == 0) red[4 + w] = q;
    __syncthreads();
    float var = (red[4] + red[5] + red[6] + red[7]) * (1.0f / HD);
    out[row * HD + t] = d * rsqrtf(var + 1e-5f) * g[t] + b[t];
}

// attention for one (b, nh, l) per block
__global__ void k_attn(const float* __restrict__ qkv, const float* __restrict__ mask,
                       float* __restrict__ o) {
    __shared__ __align__(16) float qs[64];
    __shared__ float sc[LSEQ];
    __shared__ float red[8];
    __shared__ float op[4][64];
    int bid = blockIdx.x;
    int l = bid % LSEQ;
    int nh = (bid / LSEQ) & 3;
    int b = bid / (LSEQ * NHEAD);
    int t = threadIdx.x;
    int w = t >> 6, lane = t & 63;
    const float* qbase = qkv + ((size_t)(b * LSEQ + l)) * 768 + nh * 64;
    if (t < 64) qs[t] = qbase[t];
    __syncthreads();
    float lmax = -1e30f;
    float myv[2];
#pragma unroll
    for (int it = 0; it < 2; ++it) {
        int m = t + it * 256;
        if (m < LSEQ) {
            const float* kb = qkv + ((size_t)(b * LSEQ + m)) * 768 + 256 + nh * 64;
            const float4* k4 = (const float4*)kb;
            const float4* q4 = (const float4*)qs;
            float acc = 0.0f;
#pragma unroll
            for (int a = 0; a < 16; ++a) {
                float4 kv = k4[a], qv = q4[a];
                acc += qv.x * kv.x + qv.y * kv.y + qv.z * kv.z + qv.w * kv.w;
            }
            float s = acc * 0.125f + mask[l * LSEQ + m];
            myv[it] = s;
            lmax = fmaxf(lmax, s);
        } else myv[it] = -1e30f;
    }
    float wm = wmax(lmax);
    if (lane == 0) red[w] = wm;
    __syncthreads();
    float gmax = fmaxf(fmaxf(red[0], red[1]), fmaxf(red[2], red[3]));
    float lsum = 0.0f;
#pragma unroll
    for (int it = 0; it < 2; ++it) {
        int m = t + it * 256;
        if (m < LSEQ) {
            float e = expf(myv[it] - gmax);
            sc[m] = e;
            lsum += e;
        }
    }
    float ws = wsum(lsum);
    if (lane == 0) red[4 + w] = ws;
    __syncthreads();
    float inv = 1.0f / (red[4] + red[5] + red[6] + red[7]);
    int d = t & 63, gq = t >> 6;
    float part = 0.0f;
    for (int m = gq * 96; m < (gq + 1) * 96; ++m)
        part += sc[m] * qkv[((size_t)(b * LSEQ + m)) * 768 + 512 + nh * 64 + d];
    op[gq][d] = part;
    __syncthreads();
    if (t < 64) {
        float ov = (op[0][t] + op[1][t] + op[2][t] + op[3][t]) * inv;
        o[((size_t)(b * LSEQ + l)) * HD + nh * 64 + t] = ov;
    }
}

// ============ MFMA pair-update v4: 2-phase LDS weights, min LDS footprint ============
// Block = 256 threads = 4 waves, 128 j. Weights staged ONE MLP AT A TIME into a
// 17.4KB LDS buffer (re-stage hides under gelu). DIST aliases its 33KB output
// tile over the weight buffer (lw dead by then) and reorders fragments->k-order
// entirely in registers via shfl_xor(32) — no mid-kernel LDS tile.
template<bool DIST>
__global__ void __launch_bounds__(256) k_pair_upd(
    const float* __restrict__ ojc,   // centered oj         (B,L,64)
    const float* __restrict__ oic,   // centered oi+outer_b (B,L,64)
    const unsigned short* __restrict__ w1hT, const unsigned short* __restrict__ w1lT,
    const float* __restrict__ b1p,
    const unsigned short* __restrict__ w2hT, const unsigned short* __restrict__ w2lT,
    const float* __restrict__ b2, float* __restrict__ pair,
    const float* __restrict__ gpb, const float* __restrict__ cbv,
    float* __restrict__ mask_out,
    const unsigned short* __restrict__ dw1h, const unsigned short* __restrict__ dw1l,
    const float* __restrict__ db1p,
    const unsigned short* __restrict__ dw2h, const unsigned short* __restrict__ dw2l,
    const float* __restrict__ w2c, const float* __restrict__ db2,
    float* __restrict__ outg) {
    __shared__ __align__(16) char smem[DIST ? 33344 : 17472];
    short (*lw)[64][68] = (short (*)[64][68])smem;   // [2][64][68] hi|lo, padded
    int blk = blockIdx.x;            // row*3 + seg
    int row = blk / 3, seg = blk % 3;
    int b = row / LSEQ;
    int t = threadIdx.x;
    int wave = t >> 6, lane = t & 63;
    int pl = lane & 31, hq = lane >> 5;
    int jj = wave * 32 + pl;         // 0..127 within segment
    int p = seg * 128 + jj;
    const float* ojr = ojc + ((size_t)b * LSEQ + p) * 64;
    const float* oir = oic + (size_t)row * 64;
    float* prp = pair + ((size_t)row * LSEQ + p) * 64;

#define STAGE2(srcA, srcB) \
    for (int idx = t; idx < 2048; idx += 256) { \
        int rr2 = idx >> 5, cc2 = (idx & 31) * 2; \
        *(unsigned*)&lw[0][rr2][cc2] = *(const unsigned*)(srcA + rr2 * 64 + cc2); \
        *(unsigned*)&lw[1][rr2][cc2] = *(const unsigned*)(srcB + rr2 * 64 + cc2); \
    }

    // ---- v = oj + oi, vectorized ----
    float v[32];
    {
        const f32x4* a4 = (const f32x4*)ojr;
        const f32x4* c4 = (const f32x4*)oir;
#pragma unroll
        for (int s = 0; s < 4; ++s) {
            f32x4 a = a4[4 * s + 2 * hq], aa = a4[4 * s + 2 * hq + 1];
            f32x4 c = c4[4 * s + 2 * hq], cc = c4[4 * s + 2 * hq + 1];
#pragma unroll
            for (int j = 0; j < 4; ++j) {
                v[8 * s + j] = a[j] + c[j];
                v[8 * s + 4 + j] = aa[j] + cc[j];
            }
        }
    }
    STAGE2(w1hT, w1lT)

    // LN (mean removed upstream) + bf16 hi/lo pack via cvt_pk
    float ss = 0.0f;
#pragma unroll
    for (int i = 0; i < 32; ++i) ss = fmaf(v[i], v[i], ss);
    ss += __shfl_xor(ss, 32);
    float rs = rsqrtf(ss * (1.0f / PDIM) + 1e-5f);
#pragma unroll
    for (int i = 0; i < 32; ++i) v[i] *= rs;
    u32x4 zh[4], zl[4];
#pragma unroll
    for (int s = 0; s < 4; ++s) pack8(v + 8 * s, zh[s], zl[s]);

    const f32x4* b14 = (const f32x4*)b1p;
    f32x4 bi0[4], bi1[4];
#pragma unroll
    for (int g = 0; g < 4; ++g) { bi0[g] = b14[2 * g + hq]; bi1[g] = b14[8 + 2 * g + hq]; }

    __syncthreads();   // w1 staged

    f32x16 acc0, acc1;
#pragma unroll
    for (int r = 0; r < 16; ++r) {
        acc0[r] = bi0[r >> 2][r & 3];
        acc1[r] = bi1[r >> 2][r & 3];
    }
#pragma unroll
    for (int s = 0; s < 4; ++s) {
        int ko = 16 * s + 8 * hq;
        bf16x8 a0h = ld8(&lw[0][pl][ko]);
        bf16x8 a0l = ld8(&lw[1][pl][ko]);
        bf16x8 a1h = ld8(&lw[0][32 + pl][ko]);
        bf16x8 a1l = ld8(&lw[1][32 + pl][ko]);
        bf16x8 zhs = as_bf(zh[s]), zls = as_bf(zl[s]);
        acc0 = MFMA32(a0h, zhs, acc0);
        acc0 = MFMA32(a0h, zls, acc0);
        acc0 = MFMA32(a0l, zhs, acc0);
        acc1 = MFMA32(a1h, zhs, acc1);
        acc1 = MFMA32(a1h, zls, acc1);
        acc1 = MFMA32(a1l, zhs, acc1);
    }
    __syncthreads();   // all waves done reading w1
    STAGE2(w2hT, w2lT)  // load latency hides under gelu below

    float u0[16], u1[16];
#pragma unroll
    for (int r = 0; r < 16; ++r) { u0[r] = gelu_erf(acc0[r]); u1[r] = gelu_erf(acc1[r]); }

    // residual + bias2 prefetch
    f32x4 r0[4], r1[4], q0[4], q1[4];
    {
        const f32x4* pr4 = (const f32x4*)prp;
        const f32x4* b24 = (const f32x4*)b2;
#pragma unroll
        for (int g = 0; g < 4; ++g) {
            r0[g] = pr4[2 * g + hq];
            r1[g] = pr4[8 + 2 * g + hq];
            q0[g] = b24[2 * g + hq];
            q1[g] = b24[8 + 2 * g + hq];
        }
    }

    float rA0[4], rB0[4], rA1[4], rB1[4];
#pragma unroll
    for (int i = 0; i < 4; ++i) {
        rA0[i] = __shfl_xor(hq ? u0[i] : u0[4 + i], 32);
        rB0[i] = __shfl_xor(hq ? u0[8 + i] : u0[12 + i], 32);
        rA1[i] = __shfl_xor(hq ? u1[i] : u1[4 + i], 32);
        rB1[i] = __shfl_xor(hq ? u1[8 + i] : u1[12 + i], 32);
    }
    u32x4 uh[4], ul[4];
#pragma unroll
    for (int s = 0; s < 4; ++s) {
        int tt = s >> 1, q = s & 1;
        float fg[8];
#pragma unroll
        for (int i = 0; i < 4; ++i) {
            float own_f = q ? (tt ? u1[8 + i] : u0[8 + i]) : (tt ? u1[i] : u0[i]);
            float own_s = q ? (tt ? u1[12 + i] : u0[12 + i]) : (tt ? u1[4 + i] : u0[4 + i]);
            float rcv   = q ? (tt ? rB1[i] : rB0[i]) : (tt ? rA1[i] : rA0[i]);
            fg[i]     = hq ? rcv : own_f;
            fg[4 + i] = hq ? own_s : rcv;
        }
        pack8(fg, uh[s], ul[s]);
    }

    __syncthreads();   // w2 staged

    f32x16 c0, c1;
#pragma unroll
    for (int r = 0; r < 16; ++r) {
        int g = r >> 2, i = r & 3;
        c0[r] = q0[g][i] + r0[g][i];
        c1[r] = q1[g][i] + r1[g][i];
    }
#pragma unroll
    for (int s = 0; s < 4; ++s) {
        int ko = 16 * s + 8 * hq;
        bf16x8 a0h = ld8(&lw[0][pl][ko]);
        bf16x8 a0l = ld8(&lw[1][pl][ko]);
        bf16x8 a1h = ld8(&lw[0][32 + pl][ko]);
        bf16x8 a1l = ld8(&lw[1][32 + pl][ko]);
        bf16x8 uhs = as_bf(uh[s]), uls = as_bf(ul[s]);
        c0 = MFMA32(a0h, uhs, c0);
        c0 = MFMA32(a0h, uls, c0);
        c0 = MFMA32(a0l, uhs, c0);
        c1 = MFMA32(a1h, uhs, c1);
        c1 = MFMA32(a1h, uls, c1);
        c1 = MFMA32(a1l, uhs, c1);
    }

    if constexpr (!DIST) {
        // fused mask for next layer: LN(final pair) . pbsum, mean over b via atomics
        const f32x4* gp4 = (const f32x4*)gpb;
        f32x4 gp0[4], gp1[4];
#pragma unroll
        for (int g = 0; g < 4; ++g) { gp0[g] = gp4[2 * g + hq]; gp1[g] = gp4[8 + 2 * g + hq]; }
        float sv = 0.0f;
#pragma unroll
        for (int r = 0; r < 16; ++r) sv += c0[r] + c1[r];
        sv += __shfl_xor(sv, 32);
        float mean = sv * (1.0f / PDIM);
        float sd2 = 0.0f, sdg = 0.0f;
#pragma unroll 4
        for (int r = 0; r < 16; ++r) {
            int g = r >> 2, i = r & 3;
            float d0 = c0[r] - mean, d1 = c1[r] - mean;
            sd2 = fmaf(d0, d0, sd2);
            sd2 = fmaf(d1, d1, sd2);
            sdg = fmaf(d0, gp0[g][i], sdg);
            sdg = fmaf(d1, gp1[g][i], sdg);
        }
        sd2 += __shfl_xor(sd2, 32);
        sdg += __shfl_xor(sdg, 32);
        float rsv = rsqrtf(sd2 * (1.0f / PDIM) + 1e-5f);
        float dot = rsv * sdg + cbv[0];
        if (hq == 0)
            atomicAdd(mask_out + (row % LSEQ) * LSEQ + p, dot * (1.0f / (BATCH * NHEAD)));
        // store updated pair: lane-private float4 x8
        f32x4* pw4 = (f32x4*)prp;
#pragma unroll
        for (int g = 0; g < 4; ++g) {
            f32x4 s0, s1;
#pragma unroll
            for (int i = 0; i < 4; ++i) { s0[i] = c0[4 * g + i]; s1[i] = c1[4 * g + i]; }
            pw4[2 * g + hq] = s0;
            pw4[8 + 2 * g + hq] = s1;
        }
    } else {
        // ---- fused distogram head; fragment->k-order reorder in registers ----
        // partner lane (xor 32) holds exactly the interleaved 4-channel groups:
        float ra[4], rb[4], rc[4], rd[4];
#pragma unroll
        for (int i = 0; i < 4; ++i) {
            ra[i] = __shfl_xor(hq ? c0[i] : c0[4 + i], 32);
            rb[i] = __shfl_xor(hq ? c0[8 + i] : c0[12 + i], 32);
            rc[i] = __shfl_xor(hq ? c1[i] : c1[4 + i], 32);
            rd[i] = __shfl_xor(hq ? c1[8 + i] : c1[12 + i], 32);
        }
        float v2[32];
#pragma unroll
        for (int i = 0; i < 4; ++i) {
            v2[i]      = hq ? ra[i] : c0[i];
            v2[4 + i]  = hq ? c0[4 + i] : ra[i];
            v2[8 + i]  = hq ? rb[i] : c0[8 + i];
            v2[12 + i] = hq ? c0[12 + i] : rb[i];
            v2[16 + i] = hq ? rc[i] : c1[i];
            v2[20 + i] = hq ? c1[4 + i] : rc[i];
            v2[24 + i] = hq ? rd[i] : c1[8 + i];
            v2[28 + i] = hq ? c1[12 + i] : rd[i];
        }
        __syncthreads();   // all waves done reading pu w2
        STAGE2(dw1h, dw1l)

        float sm = 0.0f;
#pragma unroll
        for (int i = 0; i < 32; ++i) sm += v2[i];
        sm += __shfl_xor(sm, 32);
        float mean = sm * (1.0f / PDIM);
        float ss2 = 0.0f;
#pragma unroll
        for (int i = 0; i < 32; ++i) { v2[i] -= mean; ss2 = fmaf(v2[i], v2[i], ss2); }
        ss2 += __shfl_xor(ss2, 32);
        float rs2 = rsqrtf(ss2 * (1.0f / PDIM) + 1e-5f);
#pragma unroll
        for (int i = 0; i < 32; ++i) v2[i] *= rs2;
#pragma unroll
        for (int s = 0; s < 4; ++s) pack8(v2 + 8 * s, zh[s], zl[s]);

        const f32x4* d14 = (const f32x4*)db1p;
        const f32x4* d24 = (const f32x4*)db2;
        const f32x4* wc4 = (const f32x4*)w2c;
        f32x4 di0[4], di1[4], e0[4], e1[4], wc0[4], wc1[4];
#pragma unroll
        for (int g = 0; g < 4; ++g) {
            di0[g] = d14[2 * g + hq]; di1[g] = d14[8 + 2 * g + hq];
            e0[g] = d24[2 * g + hq];  e1[g] = d24[8 + 2 * g + hq];
            wc0[g] = wc4[2 * g + hq]; wc1[g] = wc4[8 + 2 * g + hq];
        }
        __syncthreads();   // dw1 staged

#pragma unroll
        for (int r = 0; r < 16; ++r) {
            acc0[r] = di0[r >> 2][r & 3];
            acc1[r] = di1[r >> 2][r & 3];
        }
#pragma unroll
        for (int s = 0; s < 4; ++s) {
            int ko = 16 * s + 8 * hq;
            bf16x8 a0h = ld8(&lw[0][pl][ko]);
            bf16x8 a0l = ld8(&lw[1][pl][ko]);
            bf16x8 a1h = ld8(&lw[0][32 + pl][ko]);
            bf16x8 a1l = ld8(&lw[1][32 + pl][ko]);
            bf16x8 zhs = as_bf(zh[s]), zls = as_bf(zl[s]);
            acc0 = MFMA32(a0h, zhs, acc0);
            acc0 = MFMA32(a0h, zls, acc0);
            acc0 = MFMA32(a0l, zhs, acc0);
            acc1 = MFMA32(a1h, zhs, acc1);
            acc1 = MFMA32(a1h, zls, acc1);
            acc1 = MFMA32(a1l, zhs, acc1);
        }
        __syncthreads();   // done reading dw1
        STAGE2(dw2h, dw2l)

        float p64 = 0.0f;
#pragma unroll
        for (int r = 0; r < 16; ++r) {
            int g = r >> 2, i = r & 3;
            u0[r] = gelu_erf(acc0[r]);
            u1[r] = gelu_erf(acc1[r]);
            p64 = fmaf(u0[r], wc0[g][i], p64);
            p64 = fmaf(u1[r], wc1[g][i], p64);
        }
        p64 += __shfl_xor(p64, 32);
#pragma unroll
        for (int i = 0; i < 4; ++i) {
            rA0[i] = __shfl_xor(hq ? u0[i] : u0[4 + i], 32);
            rB0[i] = __shfl_xor(hq ? u0[8 + i] : u0[12 + i], 32);
            rA1[i] = __shfl_xor(hq ? u1[i] : u1[4 + i], 32);
            rB1[i] = __shfl_xor(hq ? u1[8 + i] : u1[12 + i], 32);
        }
#pragma unroll
        for (int s = 0; s < 4; ++s) {
            int tt = s >> 1, q = s & 1;
            float fg[8];
#pragma unroll
            for (int i = 0; i < 4; ++i) {
                float own_f = q ? (tt ? u1[8 + i] : u0[8 + i]) : (tt ? u1[i] : u0[i]);
                float own_s = q ? (tt ? u1[12 + i] : u0[12 + i]) : (tt ? u1[4 + i] : u0[4 + i]);
                float rcv   = q ? (tt ? rB1[i] : rB0[i]) : (tt ? rA1[i] : rA0[i]);
                fg[i]     = hq ? rcv : own_f;
                fg[4 + i] = hq ? own_s : rcv;
            }
            pack8(fg, uh[s], ul[s]);
        }
        __syncthreads();   // dw2 staged

#pragma unroll
        for (int r = 0; r < 16; ++r) {
            c0[r] = e0[r >> 2][r & 3];
            c1[r] = e1[r >> 2][r & 3];
        }
#pragma unroll
        for (int s = 0; s < 4; ++s) {
            int ko = 16 * s + 8 * hq;
            bf16x8 a0h = ld8(&lw[0][pl][ko]);
            bf16x8 a0l = ld8(&lw[1][pl][ko]);
            bf16x8 a1h = ld8(&lw[0][32 + pl][ko]);
            bf16x8 a1l = ld8(&lw[1][32 + pl][ko]);
            bf16x8 uhs = as_bf(uh[s]), uls = as_bf(ul[s]);
            c0 = MFMA32(a0h, uhs, c0);
            c0 = MFMA32(a0h, uls, c0);
            c0 = MFMA32(a0l, uhs, c0);
            c1 = MFMA32(a1h, uhs, c1);
            c1 = MFMA32(a1h, uls, c1);
            c1 = MFMA32(a1l, uhs, c1);
        }
        __syncthreads();   // lw dead everywhere -> reuse smem as output tile
        float (*pt)[65] = (float (*)[65])smem;
#pragma unroll
        for (int r = 0; r < 16; ++r) {
            int rr = (r & 3) + 8 * (r >> 2) + 4 * hq;
            pt[jj][rr] = c0[r];
            pt[jj][32 + rr] = c1[r];
        }
        if (hq == 0) pt[jj][64] = p64 + db2[64];
        __syncthreads();
        float4* dst = (float4*)(outg + ((size_t)row * LSEQ + seg * 128) * NBINS);
        const float4* srcl = (const float4*)&pt[0][0];
        for (int n = t; n < 128 * NBINS / 4; n += 256) dst[n] = srcl[n];
    }
#undef STAGE2
}

// out = (out + out^T(1,2)) / 2, in place.  One 16x16 (l,m) tile pair per block
// (upper triangle incl diagonal); lanes run along the contiguous 65-bin axis.
__global__ void k_sym(float* __restrict__ out) {
    int u = blockIdx.x;
    int b = 0;
    if (u >= NTRI) { b = 1; u -= NTRI; }
    int lt = 0, rem = NTT;
    while (u >= rem) { u -= rem; ++lt; --rem; }
    int mt = lt + u;
    int t = threadIdx.x;
    int g = t >> 6, lane = t & 63;
    float* ob = out + (size_t)b * LSEQ * LSEQ * NBINS;
    for (int e = g; e < 256; e += 4) {
        int i = e >> 4, j = e & 15;
        if (lt == mt && j < i) continue;
        size_t ia = ((size_t)(lt * 16 + i) * LSEQ + (mt * 16 + j)) * NBINS;
        size_t ib = ((size_t)(mt * 16 + j) * LSEQ + (lt * 16 + i)) * NBINS;
        for (int k = lane; k < NBINS; k += 64) {
            float a = ob[ia + k], c = ob[ib + k];
            float vv = 0.5f * (a + c);
            ob[ia + k] = vv;
            if (ia != ib) ob[ib + k] = vv;
        }
    }
}

extern "C" void kernel_launch(void* const* d_in, const int* in_sizes, int n_in,
                              void* d_out, int out_size, void* d_ws, size_t ws_size,
                              hipStream_t stream) {
    const float* x        = (const float*)d_in[0];
    const float* rp_w     = (const float*)d_in[1];
    const float* rp_b     = (const float*)d_in[2];
    const float* pos      = (const float*)d_in[3];
    const float* pii_w    = (const float*)d_in[4];
    const float* pii_b    = (const float*)d_in[5];
    const float* pij_w    = (const float*)d_in[6];
    const float* pij_b    = (const float*)d_in[7];
    const float* rel_emb  = (const float*)d_in[8];
    const float* ln_seq_g = (const float*)d_in[9];
    const float* ln_seq_b = (const float*)d_in[10];
    const float* ln_pair_g= (const float*)d_in[11];
    const float* ln_pair_b= (const float*)d_in[12];
    const float* pb_w     = (const float*)d_in[13];
    const float* in_w     = (const float*)d_in[14];
    const float* in_b     = (const float*)d_in[15];
    const float* out_w    = (const float*)d_in[16];
    const float* out_b    = (const float*)d_in[17];
    const float* ff_ln_g  = (const float*)d_in[18];
    const float* ff_ln_b  = (const float*)d_in[19];
    const float* ff_w1    = (const float*)d_in[20];
    const float* ff_b1    = (const float*)d_in[21];
    const float* ff_w2    = (const float*)d_in[22];
    const float* ff_b2    = (const float*)d_in[23];
    const float* pu_ln_g  = (const float*)d_in[24];
    const float* pu_ln_b  = (const float*)d_in[25];
    const float* pu_w1    = (const float*)d_in[26];
    const float* pu_b1    = (const float*)d_in[27];
    const float* pu_w2    = (const float*)d_in[28];
    const float* pu_b2    = (const float*)d_in[29];
    const float* outer_w  = (const float*)d_in[30];
    const float* outer_b  = (const float*)d_in[31];
    const float* dh_ln_g  = (const float*)d_in[32];
    const float* dh_ln_b  = (const float*)d_in[33];
    const float* dh_w1    = (const float*)d_in[34];
    const float* dh_b1    = (const float*)d_in[35];
    const float* dh_w2    = (const float*)d_in[36];
    const float* dh_b2    = (const float*)d_in[37];
    float* outp = (float*)d_out;

    float* W = (float*)d_ws;
    float* h    = W;  W += BATCH * LSEQ * HD;
    float* sn   = W;  W += BATCH * LSEQ * HD;
    float* qkv  = W;  W += BATCH * LSEQ * 3 * HD;
    float* ob   = W;  W += BATCH * LSEQ * HD;
    float* mid  = W;  W += BATCH * LSEQ * 4 * HD;
    float* maskA= W;  W += LSEQ * LSEQ;
    float* maskB= W;  W += LSEQ * LSEQ;
    float* poi  = W;  W += BATCH * LSEQ * PDIM;
    float* poj  = W;  W += BATCH * LSEQ * PDIM;
    float* b1p  = W;  W += 5 * 64;
    float* w2c  = W;  W += 64;
    float* gpb  = W;  W += 4 * 64;
    float* cbv  = W;  W += 64;
    unsigned short* w1hT = (unsigned short*)W;  W += 5 * 2048;
    unsigned short* w1lT = (unsigned short*)W;  W += 5 * 2048;
    unsigned short* w2hT = (unsigned short*)W;  W += 5 * 2048;
    unsigned short* w2lT = (unsigned short*)W;  W += 5 * 2048;
    // seq-GEMM split/transposed weights (bf16 hi/lo), per-layer strides in elems
    unsigned short* qwT_h = (unsigned short*)W;  W += 4 * 196608 / 2;
    unsigned short* qwT_l = (unsigned short*)W;  W += 4 * 196608 / 2;
    unsigned short* owT_h = (unsigned short*)W;  W += 4 * 65536 / 2;
    unsigned short* owT_l = (unsigned short*)W;  W += 4 * 65536 / 2;
    unsigned short* f1T_h = (unsigned short*)W;  W += 4 * 262144 / 2;
    unsigned short* f1T_l = (unsigned short*)W;  W += 4 * 262144 / 2;
    unsigned short* f2T_h = (unsigned short*)W;  W += 4 * 262144 / 2;
    unsigned short* f2T_l = (unsigned short*)W;  W += 4 * 262144 / 2;
    float* pair = W;  W += (size_t)BATCH * LSEQ * LSEQ * PDIM;

    const int rows = BATCH * LSEQ;   // 768

    k_prep<<<5, 64, 0, stream>>>(pu_ln_g, pu_ln_b, pu_w1, pu_b1, pu_w2,
                                 dh_ln_g, dh_ln_b, dh_w1, dh_b1, dh_w2,
                                 w1hT, w1lT, w2hT, w2lT, b1p, w2c);
    k_maskprep<<<4, 64, 0, stream>>>(ln_pair_g, ln_pair_b, pb_w, gpb, cbv);
    k_split_T<<<4 * 4 * 12, 256, 0, stream>>>(in_w,  qwT_h, qwT_l, 256, 768,  4, 12, 196608, 196608);
    k_split_T<<<4 * 4 * 4,  256, 0, stream>>>(out_w, owT_h, owT_l, 256, 256,  4, 4,  65536,  65536);
    k_split_T<<<4 * 4 * 16, 256, 0, stream>>>(ff_w1, f1T_h, f1T_l, 256, 1024, 4, 16, 262144, 262144);
    k_split_T<<<4 * 16 * 4, 256, 0, stream>>>(ff_w2, f2T_h, f2T_l, 1024, 256, 16, 4, 262144, 262144);
    k_h_init<<<rows, 256, 0, stream>>>(x, rp_w, rp_b, pos, h);
    k_proj2<<<rows, 128, 0, stream>>>(h, pii_w, pij_w, pii_b, pij_b, 0, poi, poj);
    hipMemsetAsync(maskA, 0, LSEQ * LSEQ * sizeof(float), stream);
    // pair init with fused layer-0 mask
    k_pair_init2<<<rows * 12, 64, 0, stream>>>(poi, poj, rel_emb, gpb, cbv, pair, maskA);

    float* mcur = maskA;
    float* mnext = maskB;
    for (int i = 0; i < 4; ++i) {
        k_ln_seq<<<rows, 256, 0, stream>>>(h, ln_seq_g + i * HD, ln_seq_b + i * HD, sn);
        // qkv = sn @ in_w + in_b   (24 x 24 tiles, 1-wave blocks)
        k_gemm<false><<<576, 64, 0, stream>>>(sn, qwT_h + i * 196608, qwT_l + i * 196608,
                                              in_b + i * 768, nullptr, qkv, 256, 768);
        k_attn<<<BATCH * NHEAD * LSEQ, 256, 0, stream>>>(qkv, mcur, ob);
        // h += ob @ out_w + out_b  (24 x 8 tiles)
        k_gemm<false><<<192, 64, 0, stream>>>(ob, owT_h + i * 65536, owT_l + i * 65536,
                                              out_b + i * 256, h, h, 256, 256);
        k_ln_seq<<<rows, 256, 0, stream>>>(h, ff_ln_g + i * HD, ff_ln_b + i * HD, sn);
        // mid = gelu(sn @ ff_w1 + b1)  (24 x 32 tiles)
        k_gemm<true><<<768, 64, 0, stream>>>(sn, f1T_h + i * 262144, f1T_l + i * 262144,
                                             ff_b1 + i * 1024, nullptr, mid, 256, 1024);
        // h += mid @ ff_w2 + b2  (24 x 8 tiles)
        k_gemm<false><<<192, 64, 0, stream>>>(mid, f2T_h + i * 262144, f2T_l + i * 262144,
                                              ff_b2 + i * 256, h, h, 1024, 256);
        // centered oi+outer_b (poi) and centered oj (poj)
        k_proj2<<<rows, 128, 0, stream>>>(h, outer_w + i * 2 * HD * PDIM,
                                          outer_w + i * 2 * HD * PDIM + HD * PDIM,
                                          outer_b + i * PDIM, nullptr, 1, poi, poj);
        if (i < 3) {
            hipMemsetAsync(mnext, 0, LSEQ * LSEQ * sizeof(float), stream);
            k_pair_upd<false><<<rows * 3, 256, 0, stream>>>(
                poj, poi,
                w1hT + i * 4096, w1lT + i * 4096, b1p + i * 64,
                w2hT + i * 4096, w2lT + i * 4096, pu_b2 + i * PDIM, pair,
                gpb + (i + 1) * 64, cbv + (i + 1), mnext,
                nullptr, nullptr, nullptr, nullptr, nullptr, nullptr, nullptr, nullptr);
            float* tmp = mcur; mcur = mnext; mnext = tmp;
        } else {
            // last layer: pair update fused with distogram head; pair never stored
            k_pair_upd<true><<<rows * 3, 256, 0, stream>>>(
                poj, poi,
                w1hT + 3 * 4096, w1lT + 3 * 4096, b1p + 3 * 64,
                w2hT + 3 * 4096, w2lT + 3 * 4096, pu_b2 + 3 * PDIM, pair,
                nullptr, nullptr, nullptr,
                w1hT + 4 * 4096, w1lT + 4 * 4096, b1p + 4 * 64,
                w2hT + 4 * 4096, w2lT + 4 * 4096, w2c, dh_b2, outp);
        }
    }

    k_sym<<<2 * NTRI, 256, 0, stream>>>(outp);
}